// Round 1
// baseline (730.496 us; speedup 1.0000x reference)
//
#include <hip/hip_runtime.h>
#include <hip/hip_bf16.h>
#include <cstdint>
#include <cstddef>

// ---------------------------------------------------------------------------
// FlowformerLayer: LN1 -> flow-attention(batch0) -> +res -> LN2 -> MLP -> +res
// B=2, L=16384, D=512, H=8, DH=64, F=2048
// ---------------------------------------------------------------------------

#define L_SEQ 16384
#define EPSF 1e-6f

typedef __bf16 b16x8 __attribute__((ext_vector_type(8)));
typedef __bf16 b16x4 __attribute__((ext_vector_type(4)));
typedef float  f32x4 __attribute__((ext_vector_type(4)));

__device__ __forceinline__ void gload16(const void* g, void* l) {
  __builtin_amdgcn_global_load_lds((const __attribute__((address_space(1))) void*)g,
                                   (__attribute__((address_space(3))) void*)l, 16, 0, 0);
}

__device__ __forceinline__ float sigmoidf_(float x) { return 1.f / (1.f + __expf(-x)); }

// ---------------- weight convert + transpose: dst[n*K+k] = bf16(src[k*N+n])
__global__ __launch_bounds__(256) void convT(const float* __restrict__ src,
                                             __bf16* __restrict__ dst, int K, int N) {
  __shared__ float tile[32][33];
  const int k0 = blockIdx.y * 32, n0 = blockIdx.x * 32;
  const int tx = threadIdx.x & 31, ty = threadIdx.x >> 5;  // 32 x 8
#pragma unroll
  for (int i = 0; i < 32; i += 8) tile[ty + i][tx] = src[(size_t)(k0 + ty + i) * N + n0 + tx];
  __syncthreads();
#pragma unroll
  for (int i = 0; i < 32; i += 8)
    dst[(size_t)(n0 + ty + i) * K + k0 + tx] = (__bf16)tile[tx][ty + i];
}

__global__ __launch_bounds__(256) void biascat_k(const float* __restrict__ bq,
                                                 const float* __restrict__ bk,
                                                 const float* __restrict__ bv,
                                                 float* __restrict__ bc) {
  int i = blockIdx.x * 256 + threadIdx.x;  // 1536 total
  bc[i] = (i < 512) ? bq[i] : (i < 1024) ? bk[i - 512] : bv[i - 1024];
}

__global__ __launch_bounds__(256) void zero_k(float* __restrict__ p, int n) {
  int i = blockIdx.x * 256 + threadIdx.x;
  if (i < n) p[i] = 0.f;
}

// ---------------- LayerNorm over D=512, one row per block (128 thr x float4)
__global__ __launch_bounds__(128) void ln_rows(const float* __restrict__ x,
                                               const float* __restrict__ g,
                                               const float* __restrict__ be,
                                               __bf16* __restrict__ out) {
  const int row = blockIdx.x, t = threadIdx.x;
  const float4 xv = reinterpret_cast<const float4*>(x + (size_t)row * 512)[t];
  float s = xv.x + xv.y + xv.z + xv.w;
  float s2 = xv.x * xv.x + xv.y * xv.y + xv.z * xv.z + xv.w * xv.w;
#pragma unroll
  for (int off = 32; off > 0; off >>= 1) { s += __shfl_down(s, off); s2 += __shfl_down(s2, off); }
  __shared__ float red[4];
  if ((t & 63) == 0) { red[(t >> 6) * 2] = s; red[(t >> 6) * 2 + 1] = s2; }
  __syncthreads();
  const float S = red[0] + red[2], S2 = red[1] + red[3];
  const float mean = S * (1.f / 512.f);
  const float var = S2 * (1.f / 512.f) - mean * mean;
  const float inv = rsqrtf(var + 1e-5f);
  const float4 gv = reinterpret_cast<const float4*>(g)[t];
  const float4 bv = reinterpret_cast<const float4*>(be)[t];
  b16x4 o;
  o[0] = (__bf16)((xv.x - mean) * inv * gv.x + bv.x);
  o[1] = (__bf16)((xv.y - mean) * inv * gv.y + bv.y);
  o[2] = (__bf16)((xv.z - mean) * inv * gv.z + bv.z);
  o[3] = (__bf16)((xv.w - mean) * inv * gv.w + bv.w);
  reinterpret_cast<b16x4*>(out + (size_t)row * 512)[t] = o;
}

// ---------------- residual + LayerNorm: x2 = x + sa(broadcast); d_out=x2; ln2=LN(x2)
__global__ __launch_bounds__(128) void x2ln2_k(const float* __restrict__ x,
                                               const float* __restrict__ sa,
                                               const float* __restrict__ g,
                                               const float* __restrict__ be,
                                               float* __restrict__ xout,
                                               __bf16* __restrict__ lnout) {
  const int row = blockIdx.x, t = threadIdx.x;
  const int l = row & (L_SEQ - 1);
  float4 xv = reinterpret_cast<const float4*>(x + (size_t)row * 512)[t];
  const float4 sv = reinterpret_cast<const float4*>(sa + (size_t)l * 512)[t];
  xv.x += sv.x; xv.y += sv.y; xv.z += sv.z; xv.w += sv.w;
  reinterpret_cast<float4*>(xout + (size_t)row * 512)[t] = xv;
  float s = xv.x + xv.y + xv.z + xv.w;
  float s2 = xv.x * xv.x + xv.y * xv.y + xv.z * xv.z + xv.w * xv.w;
#pragma unroll
  for (int off = 32; off > 0; off >>= 1) { s += __shfl_down(s, off); s2 += __shfl_down(s2, off); }
  __shared__ float red[4];
  if ((t & 63) == 0) { red[(t >> 6) * 2] = s; red[(t >> 6) * 2 + 1] = s2; }
  __syncthreads();
  const float S = red[0] + red[2], S2 = red[1] + red[3];
  const float mean = S * (1.f / 512.f);
  const float var = S2 * (1.f / 512.f) - mean * mean;
  const float inv = rsqrtf(var + 1e-5f);
  const float4 gv = reinterpret_cast<const float4*>(g)[t];
  const float4 bv = reinterpret_cast<const float4*>(be)[t];
  b16x4 o;
  o[0] = (__bf16)((xv.x - mean) * inv * gv.x + bv.x);
  o[1] = (__bf16)((xv.y - mean) * inv * gv.y + bv.y);
  o[2] = (__bf16)((xv.z - mean) * inv * gv.z + bv.z);
  o[3] = (__bf16)((xv.w - mean) * inv * gv.w + bv.w);
  reinterpret_cast<b16x4*>(lnout + (size_t)row * 512)[t] = o;
}

// ---------------- GEMM: C = A[M,K](bf16) @ Bt[N,K]^T(bf16), fused epilogues
// EPI 0: QKV  (+biascat, sigmoid cols<1024, scatter f32 -> q/k/v)
// EPI 1: SA   (+bias -> f32 out, stride N)
// EPI 2: GELU (+bias, exact gelu -> bf16 out, stride N)
// EPI 3: OUT  (f0[row,col] += acc + bias  -- final residual into d_out)
template <int EPI>
__global__ __launch_bounds__(256) void gemm_bt(const __bf16* __restrict__ A,
                                               const __bf16* __restrict__ Bt,
                                               const int M, const int N, const int K,
                                               const float* __restrict__ bias,
                                               float* __restrict__ f0,
                                               __bf16* __restrict__ h0,
                                               float* __restrict__ f1,
                                               float* __restrict__ f2) {
  __shared__ alignas(16) __bf16 lsA[128 * 32];
  __shared__ alignas(16) __bf16 lsB[128 * 32];
  const int bm = blockIdx.y * 128;
  const int bn = blockIdx.x * 128;
  const int t = threadIdx.x;
  const int lane = t & 63, wv = t >> 6;
  const int wr = wv >> 1, wc = wv & 1;

  f32x4 acc[4][4] = {};

  const int rowS = t >> 2;          // staging row within tile (0..63)
  const int kcS = (t & 3) * 8;      // staging k-subchunk

  for (int k0 = 0; k0 < K; k0 += 32) {
    const __bf16* gA = A + (size_t)(bm + rowS) * K + (k0 + kcS);
    const __bf16* gB = Bt + (size_t)(bn + rowS) * K + (k0 + kcS);
    gload16(gA, &lsA[(wv * 64) * 8]);
    gload16(gA + (size_t)64 * K, &lsA[(256 + wv * 64) * 8]);
    gload16(gB, &lsB[(wv * 64) * 8]);
    gload16(gB + (size_t)64 * K, &lsB[(256 + wv * 64) * 8]);
    __syncthreads();

    b16x8 af[4], bf[4];
    const int koff = (lane >> 4) * 8;
    const int rsel = lane & 15;
#pragma unroll
    for (int m = 0; m < 4; m++)
      af[m] = *reinterpret_cast<const b16x8*>(&lsA[(wr * 64 + m * 16 + rsel) * 32 + koff]);
#pragma unroll
    for (int n = 0; n < 4; n++)
      bf[n] = *reinterpret_cast<const b16x8*>(&lsB[(wc * 64 + n * 16 + rsel) * 32 + koff]);
#pragma unroll
    for (int m = 0; m < 4; m++)
#pragma unroll
      for (int n = 0; n < 4; n++)
        acc[m][n] = __builtin_amdgcn_mfma_f32_16x16x32_bf16(af[m], bf[n], acc[m][n], 0, 0, 0);
    __syncthreads();
  }

  const int r0 = (lane >> 4) * 4;
  const int cc = lane & 15;
#pragma unroll
  for (int m = 0; m < 4; m++) {
#pragma unroll
    for (int n = 0; n < 4; n++) {
      const int col = bn + wc * 64 + n * 16 + cc;
#pragma unroll
      for (int r = 0; r < 4; r++) {
        const int row = bm + wr * 64 + m * 16 + r0 + r;
        float val = acc[m][n][r];
        if constexpr (EPI == 0) {
          val += bias[col];
          if (col < 1024) val = sigmoidf_(val);
          const int which = col >> 9;
          const int c2 = col & 511;
          float* dst = (which == 0) ? f0 : (which == 1) ? f1 : f2;
          dst[(size_t)row * 512 + c2] = val;
        } else if constexpr (EPI == 1) {
          f0[(size_t)row * N + col] = val + bias[col];
        } else if constexpr (EPI == 2) {
          const float xg = val + bias[col];
          const float gel = 0.5f * xg * (1.f + erff(xg * 0.70710678118f));
          h0[(size_t)row * N + col] = (__bf16)gel;
        } else {
          const size_t idx = (size_t)row * N + col;
          f0[idx] = f0[idx] + val + bias[col];
        }
      }
    }
  }
}

// ---------------- attention reductions (all f32, batch 0 only) ----------------
// column sums of q and k: qsum[c] = sum_l q[l,c]
__global__ __launch_bounds__(256) void colsums(const float* __restrict__ q,
                                               const float* __restrict__ k,
                                               float* __restrict__ qsum,
                                               float* __restrict__ ksum) {
  const int t = threadIdx.x;
  const int l0 = blockIdx.x * 256;
  float a0 = 0, a1 = 0, b0 = 0, b1 = 0;
  for (int i = 0; i < 256; i++) {
    const float* qr = q + (size_t)(l0 + i) * 512;
    const float* kr = k + (size_t)(l0 + i) * 512;
    a0 += qr[t]; a1 += qr[t + 256];
    b0 += kr[t]; b1 += kr[t + 256];
  }
  atomicAdd(&qsum[t], a0); atomicAdd(&qsum[t + 256], a1);
  atomicAdd(&ksum[t], b0); atomicAdd(&ksum[t + 256], b1);
}

// si[h,l] = 1/sum_d (q+EPS)(ksum+EPS);  so[h,l] = 1/sum_d (k+EPS)(qsum+EPS)
__global__ __launch_bounds__(256) void rowdots1(const float* __restrict__ q,
                                                const float* __restrict__ k,
                                                const float* __restrict__ qsum,
                                                const float* __restrict__ ksum,
                                                float* __restrict__ si,
                                                float* __restrict__ so) {
  const int lane = threadIdx.x & 63, wv = threadIdx.x >> 6;
  const int l = blockIdx.x * 4 + wv;
  const float* qr = q + (size_t)l * 512;
  const float* kr = k + (size_t)l * 512;
#pragma unroll
  for (int h = 0; h < 8; h++) {
    const int c = h * 64 + lane;
    float p1 = (qr[c] + EPSF) * (ksum[c] + EPSF);
    float p2 = (kr[c] + EPSF) * (qsum[c] + EPSF);
#pragma unroll
    for (int off = 32; off > 0; off >>= 1) { p1 += __shfl_down(p1, off); p2 += __shfl_down(p2, off); }
    if (lane == 0) { si[h * L_SEQ + l] = 1.f / p1; so[h * L_SEQ + l] = 1.f / p2; }
  }
}

// weighted column sums: qsi[c] = sum_l q[l,c]*si[h(c),l];  kso[c] = sum_l k[l,c]*so[h(c),l]
__global__ __launch_bounds__(256) void colsums2(const float* __restrict__ q,
                                                const float* __restrict__ k,
                                                const float* __restrict__ si,
                                                const float* __restrict__ so,
                                                float* __restrict__ qsi,
                                                float* __restrict__ kso) {
  const int t = threadIdx.x;
  const int l0 = blockIdx.x * 256;
  const int h0 = t >> 6, h1 = (t + 256) >> 6;
  float a0 = 0, a1 = 0, b0 = 0, b1 = 0;
  for (int i = 0; i < 256; i++) {
    const int l = l0 + i;
    const float* qr = q + (size_t)l * 512;
    const float* kr = k + (size_t)l * 512;
    const float si0 = si[h0 * L_SEQ + l], si1 = si[h1 * L_SEQ + l];
    const float so0 = so[h0 * L_SEQ + l], so1 = so[h1 * L_SEQ + l];
    a0 += qr[t] * si0; a1 += qr[t + 256] * si1;
    b0 += kr[t] * so0; b1 += kr[t + 256] * so1;
  }
  atomicAdd(&qsi[t], a0); atomicAdd(&qsi[t + 256], a1);
  atomicAdd(&kso[t], b0); atomicAdd(&kso[t + 256], b1);
}

// conserved sink/source; salloc = sigmoid(cs_sink); compE = exp(clip(cs_src));
// sumexp[h] += partials
__global__ __launch_bounds__(256) void rowdots2(const float* __restrict__ q,
                                                const float* __restrict__ k,
                                                const float* __restrict__ qsi,
                                                const float* __restrict__ kso,
                                                float* __restrict__ salloc,
                                                float* __restrict__ compE,
                                                float* __restrict__ sumexp) {
  __shared__ float part[8];
  if (threadIdx.x < 8) part[threadIdx.x] = 0.f;
  __syncthreads();
  const int lane = threadIdx.x & 63, wv = threadIdx.x >> 6;
  float local[8] = {0, 0, 0, 0, 0, 0, 0, 0};
#pragma unroll 1
  for (int i = 0; i < 8; i++) {
    const int l = blockIdx.x * 32 + wv * 8 + i;
    const float* qr = q + (size_t)l * 512;
    const float* kr = k + (size_t)l * 512;
#pragma unroll
    for (int h = 0; h < 8; h++) {
      const int c = h * 64 + lane;
      float p1 = (qr[c] + EPSF) * (kso[c] + EPSF);
      float p2 = (kr[c] + EPSF) * (qsi[c] + EPSF);
#pragma unroll
      for (int off = 32; off > 0; off >>= 1) { p1 += __shfl_down(p1, off); p2 += __shfl_down(p2, off); }
      if (lane == 0) {
        const float cs = fminf(fmaxf(p2, -1.f), 1.f);
        const float e = expf(cs);
        salloc[h * L_SEQ + l] = sigmoidf_(p1);
        compE[h * L_SEQ + l] = e;
        local[h] += e;
      }
    }
  }
  if (lane == 0) {
#pragma unroll
    for (int h = 0; h < 8; h++) atomicAdd(&part[h], local[h]);
  }
  __syncthreads();
  if (threadIdx.x < 8) atomicAdd(&sumexp[threadIdx.x], part[threadIdx.x]);
}

// kv[h,d,m] = sum_l k[l,hd] * v[l,hm] * compE[h,l] * (S/sumexp[h])
__global__ __launch_bounds__(256) void kv_kernel(const float* __restrict__ k,
                                                 const float* __restrict__ v,
                                                 const float* __restrict__ compE,
                                                 const float* __restrict__ sumexp,
                                                 float* __restrict__ kvout) {
  const int h = blockIdx.y;
  const int t = threadIdx.x;
  __shared__ float lsK[64 * 64];
  __shared__ float lsV[64 * 64];
  const float Sfac = (float)L_SEQ / sumexp[h];
  const int d = t & 63, mg = t >> 6;
  f32x4 acc4[4] = {};
  for (int sc = 0; sc < 8; sc++) {
    const int l0 = blockIdx.x * 512 + sc * 64;
    __syncthreads();
#pragma unroll
    for (int j = 0; j < 16; j++) {
      const int idx = t + j * 256;
      const int lr = idx >> 6, c = idx & 63;
      const int l = l0 + lr;
      const float w = compE[h * L_SEQ + l] * Sfac;
      lsK[idx] = k[(size_t)l * 512 + h * 64 + c];
      lsV[idx] = v[(size_t)l * 512 + h * 64 + c] * w;
    }
    __syncthreads();
    for (int lr = 0; lr < 64; lr++) {
      const float kd = lsK[lr * 64 + d];
      const f32x4* lv = reinterpret_cast<const f32x4*>(&lsV[lr * 64 + mg * 16]);
#pragma unroll
      for (int jj = 0; jj < 4; jj++) acc4[jj] += lv[jj] * kd;
    }
  }
#pragma unroll
  for (int jj = 0; jj < 4; jj++)
#pragma unroll
    for (int e = 0; e < 4; e++)
      atomicAdd(&kvout[h * 4096 + d * 64 + mg * 16 + jj * 4 + e], acc4[jj][e]);
}

// o[l, h*64+m] = bf16( salloc[h,l]*si[h,l] * sum_d q[l,hd]*kv[h,d,m] )
__global__ __launch_bounds__(256) void o_kernel(const float* __restrict__ q,
                                                const float* __restrict__ kvin,
                                                const float* __restrict__ si,
                                                const float* __restrict__ sal,
                                                __bf16* __restrict__ o) {
  const int h = blockIdx.y;
  const int l0 = blockIdx.x * 32;
  const int t = threadIdx.x;
  __shared__ float lsKV[64 * 64];
  __shared__ float lsQ[32 * 64];
#pragma unroll
  for (int j = 0; j < 16; j++) lsKV[t + j * 256] = kvin[h * 4096 + t + j * 256];
#pragma unroll
  for (int j = 0; j < 8; j++) {
    const int idx = t + j * 256;
    const int r = idx >> 6, c = idx & 63;
    lsQ[idx] = q[(size_t)(l0 + r) * 512 + h * 64 + c];
  }
  __syncthreads();
  const int m = t & 63, rg = t >> 6;
#pragma unroll 1
  for (int i = 0; i < 8; i++) {
    const int r = rg + i * 4;
    const int l = l0 + r;
    float a = 0.f;
#pragma unroll
    for (int d = 0; d < 64; d++) a += lsQ[r * 64 + d] * lsKV[d * 64 + m];
    const float f = sal[h * L_SEQ + l] * si[h * L_SEQ + l];
    o[(size_t)l * 512 + h * 64 + m] = (__bf16)(a * f);
  }
}

// ---------------------------------------------------------------------------
extern "C" void kernel_launch(void* const* d_in, const int* in_sizes, int n_in,
                              void* d_out, int out_size, void* d_ws, size_t ws_size,
                              hipStream_t stream) {
  const float* x  = (const float*)d_in[0];
  const float* Wq = (const float*)d_in[1];
  const float* bq = (const float*)d_in[2];
  const float* Wk = (const float*)d_in[3];
  const float* bk = (const float*)d_in[4];
  const float* Wv = (const float*)d_in[5];
  const float* bv = (const float*)d_in[6];
  const float* Wo = (const float*)d_in[7];
  const float* bo = (const float*)d_in[8];
  const float* W1 = (const float*)d_in[9];
  const float* b1 = (const float*)d_in[10];
  const float* W2 = (const float*)d_in[11];
  const float* b2 = (const float*)d_in[12];
  const float* g1 = (const float*)d_in[13];
  const float* be1 = (const float*)d_in[14];
  const float* g2 = (const float*)d_in[15];
  const float* be2 = (const float*)d_in[16];
  float* out = (float*)d_out;

  char* ws = (char*)d_ws;
  size_t off = 0;
  auto alloc = [&](size_t bytes) -> char* {
    char* p = ws + off;
    off += (bytes + 255) & ~(size_t)255;
    return p;
  };

  // Region A: attention temporaries, later reused as MLP activation (exact fit)
  char* regA = alloc(134217728);
  __bf16* ln1 = (__bf16*)regA;                       // 16384*512 bf16  (16.78 MB)
  float* qb = (float*)(regA + 16777216);             // 16384*512 f32   (33.55 MB)
  float* kb = (float*)(regA + 50331648);
  float* vb = (float*)(regA + 83886080);
  __bf16* ob = (__bf16*)(regA + 117440512);          // 16384*512 bf16
  __bf16* act = (__bf16*)regA;                       // 32768*2048 bf16 (134.2 MB)

  float* sa = (float*)alloc((size_t)16384 * 512 * 4);
  __bf16* ln2 = (__bf16*)alloc((size_t)32768 * 512 * 2);
  __bf16* Wqkvt = (__bf16*)alloc((size_t)1536 * 512 * 2);
  __bf16* Wot = (__bf16*)alloc((size_t)512 * 512 * 2);
  __bf16* W1t = (__bf16*)alloc((size_t)2048 * 512 * 2);
  __bf16* W2t = (__bf16*)alloc((size_t)512 * 2048 * 2);
  float* biascat = (float*)alloc(1536 * 4);
  float* si = (float*)alloc((size_t)8 * L_SEQ * 4);
  float* so = (float*)alloc((size_t)8 * L_SEQ * 4);
  float* sal = (float*)alloc((size_t)8 * L_SEQ * 4);
  float* compE = (float*)alloc((size_t)8 * L_SEQ * 4);
  float* stats = (float*)alloc(34880 * 4);  // qsum|ksum|qsi|kso|sumexp(64)|kv(8*4096)
  float* qsum = stats;
  float* ksum = stats + 512;
  float* qsi = stats + 1024;
  float* kso = stats + 1536;
  float* sumexp = stats + 2048;
  float* kvbuf = stats + 2112;

  // weights -> bf16 transposed
  convT<<<dim3(16, 16), 256, 0, stream>>>(Wq, Wqkvt, 512, 512);
  convT<<<dim3(16, 16), 256, 0, stream>>>(Wk, Wqkvt + (size_t)512 * 512, 512, 512);
  convT<<<dim3(16, 16), 256, 0, stream>>>(Wv, Wqkvt + (size_t)1024 * 512, 512, 512);
  convT<<<dim3(16, 16), 256, 0, stream>>>(Wo, Wot, 512, 512);
  convT<<<dim3(64, 16), 256, 0, stream>>>(W1, W1t, 512, 2048);
  convT<<<dim3(16, 64), 256, 0, stream>>>(W2, W2t, 2048, 512);
  biascat_k<<<6, 256, 0, stream>>>(bq, bk, bv, biascat);
  zero_k<<<(34880 + 255) / 256, 256, 0, stream>>>(stats, 34880);

  // LN1 (batch 0 only) -> QKV GEMM (sigmoid q,k)
  ln_rows<<<L_SEQ, 128, 0, stream>>>(x, g1, be1, ln1);
  gemm_bt<0><<<dim3(12, 128), 256, 0, stream>>>(ln1, Wqkvt, L_SEQ, 1536, 512,
                                                biascat, qb, nullptr, kb, vb);

  // flow-attention normalization chain
  colsums<<<64, 256, 0, stream>>>(qb, kb, qsum, ksum);
  rowdots1<<<L_SEQ / 4, 256, 0, stream>>>(qb, kb, qsum, ksum, si, so);
  colsums2<<<64, 256, 0, stream>>>(qb, kb, si, so, qsi, kso);
  rowdots2<<<L_SEQ / 32, 256, 0, stream>>>(qb, kb, qsi, kso, sal, compE, sumexp);
  kv_kernel<<<dim3(32, 8), 256, 0, stream>>>(kb, vb, compE, sumexp, kvbuf);
  o_kernel<<<dim3(L_SEQ / 32, 8), 256, 0, stream>>>(qb, kvbuf, si, sal, ob);

  // sa = o @ Wo + bo
  gemm_bt<1><<<dim3(4, 128), 256, 0, stream>>>(ob, Wot, L_SEQ, 512, 512,
                                               bo, sa, nullptr, nullptr, nullptr);

  // x2 = x + sa (broadcast over batch) -> d_out; ln2 = LN(x2)
  x2ln2_k<<<2 * L_SEQ, 128, 0, stream>>>(x, sa, g2, be2, out, ln2);

  // MLP: act = gelu(ln2 @ W1 + b1);  d_out += act @ W2 + b2
  gemm_bt<2><<<dim3(16, 256), 256, 0, stream>>>(ln2, W1t, 2 * L_SEQ, 2048, 512,
                                                b1, nullptr, act, nullptr, nullptr);
  gemm_bt<3><<<dim3(4, 256), 256, 0, stream>>>(act, W2t, 2 * L_SEQ, 512, 2048,
                                               b2, out, nullptr, nullptr, nullptr);
}

// Round 2
// 676.778 us; speedup vs baseline: 1.0794x; 1.0794x over previous
//
#include <hip/hip_runtime.h>
#include <hip/hip_bf16.h>
#include <cstdint>
#include <cstddef>

// ---------------------------------------------------------------------------
// FlowformerLayer: LN1 -> flow-attention(batch0) -> +res -> LN2 -> MLP -> +res
// B=2, L=16384, D=512, H=8, DH=64, F=2048
// GEMMs: 256x256 tile, BK=64, 8 waves, LDS double-buffer (1 barrier/K-tile),
//        XOR-swizzled LDS (slot ^= row&7) via pre-swizzled global source.
// ---------------------------------------------------------------------------

#define L_SEQ 16384
#define EPSF 1e-6f

typedef __bf16 b16x8 __attribute__((ext_vector_type(8)));
typedef __bf16 b16x4 __attribute__((ext_vector_type(4)));
typedef float  f32x4 __attribute__((ext_vector_type(4)));

__device__ __forceinline__ void gload16(const void* g, void* l) {
  __builtin_amdgcn_global_load_lds((const __attribute__((address_space(1))) void*)g,
                                   (__attribute__((address_space(3))) void*)l, 16, 0, 0);
}

__device__ __forceinline__ float sigmoidf_(float x) { return 1.f / (1.f + __expf(-x)); }

// ---------------- weight convert + transpose: dst[n*K+k] = bf16(src[k*N+n])
__global__ __launch_bounds__(256) void convT(const float* __restrict__ src,
                                             __bf16* __restrict__ dst, int K, int N) {
  __shared__ float tile[32][33];
  const int k0 = blockIdx.y * 32, n0 = blockIdx.x * 32;
  const int tx = threadIdx.x & 31, ty = threadIdx.x >> 5;  // 32 x 8
#pragma unroll
  for (int i = 0; i < 32; i += 8) tile[ty + i][tx] = src[(size_t)(k0 + ty + i) * N + n0 + tx];
  __syncthreads();
#pragma unroll
  for (int i = 0; i < 32; i += 8)
    dst[(size_t)(n0 + ty + i) * K + k0 + tx] = (__bf16)tile[tx][ty + i];
}

__global__ __launch_bounds__(256) void biascat_k(const float* __restrict__ bq,
                                                 const float* __restrict__ bk,
                                                 const float* __restrict__ bv,
                                                 float* __restrict__ bc) {
  int i = blockIdx.x * 256 + threadIdx.x;  // 1536 total
  bc[i] = (i < 512) ? bq[i] : (i < 1024) ? bk[i - 512] : bv[i - 1024];
}

__global__ __launch_bounds__(256) void zero_k(float* __restrict__ p, int n) {
  int i = blockIdx.x * 256 + threadIdx.x;
  if (i < n) p[i] = 0.f;
}

// ---------------- LayerNorm over D=512, one row per block (128 thr x float4)
__global__ __launch_bounds__(128) void ln_rows(const float* __restrict__ x,
                                               const float* __restrict__ g,
                                               const float* __restrict__ be,
                                               __bf16* __restrict__ out) {
  const int row = blockIdx.x, t = threadIdx.x;
  const float4 xv = reinterpret_cast<const float4*>(x + (size_t)row * 512)[t];
  float s = xv.x + xv.y + xv.z + xv.w;
  float s2 = xv.x * xv.x + xv.y * xv.y + xv.z * xv.z + xv.w * xv.w;
#pragma unroll
  for (int off = 32; off > 0; off >>= 1) { s += __shfl_down(s, off); s2 += __shfl_down(s2, off); }
  __shared__ float red[4];
  if ((t & 63) == 0) { red[(t >> 6) * 2] = s; red[(t >> 6) * 2 + 1] = s2; }
  __syncthreads();
  const float S = red[0] + red[2], S2 = red[1] + red[3];
  const float mean = S * (1.f / 512.f);
  const float var = S2 * (1.f / 512.f) - mean * mean;
  const float inv = rsqrtf(var + 1e-5f);
  const float4 gv = reinterpret_cast<const float4*>(g)[t];
  const float4 bv = reinterpret_cast<const float4*>(be)[t];
  b16x4 o;
  o[0] = (__bf16)((xv.x - mean) * inv * gv.x + bv.x);
  o[1] = (__bf16)((xv.y - mean) * inv * gv.y + bv.y);
  o[2] = (__bf16)((xv.z - mean) * inv * gv.z + bv.z);
  o[3] = (__bf16)((xv.w - mean) * inv * gv.w + bv.w);
  reinterpret_cast<b16x4*>(out + (size_t)row * 512)[t] = o;
}

// ---------------- residual + LayerNorm: x2 = x + sa(broadcast); d_out=x2; ln2=LN(x2)
__global__ __launch_bounds__(128) void x2ln2_k(const float* __restrict__ x,
                                               const float* __restrict__ sa,
                                               const float* __restrict__ g,
                                               const float* __restrict__ be,
                                               float* __restrict__ xout,
                                               __bf16* __restrict__ lnout) {
  const int row = blockIdx.x, t = threadIdx.x;
  const int l = row & (L_SEQ - 1);
  float4 xv = reinterpret_cast<const float4*>(x + (size_t)row * 512)[t];
  const float4 sv = reinterpret_cast<const float4*>(sa + (size_t)l * 512)[t];
  xv.x += sv.x; xv.y += sv.y; xv.z += sv.z; xv.w += sv.w;
  reinterpret_cast<float4*>(xout + (size_t)row * 512)[t] = xv;
  float s = xv.x + xv.y + xv.z + xv.w;
  float s2 = xv.x * xv.x + xv.y * xv.y + xv.z * xv.z + xv.w * xv.w;
#pragma unroll
  for (int off = 32; off > 0; off >>= 1) { s += __shfl_down(s, off); s2 += __shfl_down(s2, off); }
  __shared__ float red[4];
  if ((t & 63) == 0) { red[(t >> 6) * 2] = s; red[(t >> 6) * 2 + 1] = s2; }
  __syncthreads();
  const float S = red[0] + red[2], S2 = red[1] + red[3];
  const float mean = S * (1.f / 512.f);
  const float var = S2 * (1.f / 512.f) - mean * mean;
  const float inv = rsqrtf(var + 1e-5f);
  const float4 gv = reinterpret_cast<const float4*>(g)[t];
  const float4 bv = reinterpret_cast<const float4*>(be)[t];
  b16x4 o;
  o[0] = (__bf16)((xv.x - mean) * inv * gv.x + bv.x);
  o[1] = (__bf16)((xv.y - mean) * inv * gv.y + bv.y);
  o[2] = (__bf16)((xv.z - mean) * inv * gv.z + bv.z);
  o[3] = (__bf16)((xv.w - mean) * inv * gv.w + bv.w);
  reinterpret_cast<b16x4*>(lnout + (size_t)row * 512)[t] = o;
}

// ---------------- GEMM 256x256: C = A[M,K](bf16) @ Bt[N,K]^T(bf16)
// 512 threads = 8 waves (2 Mwarps x 4 Nwarps), per-wave 128x64 output.
// LDS: A dbuf 2x32KB + B dbuf 2x32KB = 128KB. BK=64.
// Swizzle: LDS row=128B, 8x16B slots; logical chunk c of row r stored at
// slot c^(r&7). gload_lds dest is linear; source address pre-swizzled.
// EPI 0: QKV (+biascat, sigmoid cols<1024, scatter f32 -> q/k/v)
// EPI 1: SA  (+bias -> f32, stride N)
// EPI 2: GELU(+bias -> bf16, stride N)
// EPI 3: OUT (f0[row,col] += acc + bias)
template <int EPI>
__global__ __launch_bounds__(512) void gemm256(const __bf16* __restrict__ A,
                                               const __bf16* __restrict__ Bt,
                                               const int M, const int N, const int K,
                                               const float* __restrict__ bias,
                                               float* __restrict__ f0,
                                               __bf16* __restrict__ h0,
                                               float* __restrict__ f1,
                                               float* __restrict__ f2) {
  __shared__ alignas(16) __bf16 lds[65536];  // 128 KB

  // XCD-aware block swizzle (all grids are %8==0)
  const int nwg = gridDim.x;
  const int orig = blockIdx.x;
  const int cpx = nwg >> 3;
  const int wg = (orig & 7) * cpx + (orig >> 3);
  const int gx = N >> 8;
  const int bm = (wg / gx) << 8;
  const int bn = (wg % gx) << 8;

  const int t = threadIdx.x;
  const int w = t >> 6, lane = t & 63;
  const int wr = w >> 2, wc = w & 3;
  const int lr = lane >> 3;                // staging row-in-group 0..7
  const int sx = (lane & 7) ^ lr;          // pre-swizzled source chunk
  const int fr = lane & 15;                // fragment row select
  const int kb = lane >> 4;                // 0..3 (16B chunk within k-step)
  const int l7 = lane & 7;

  // per-lane staging base pointers (advance by k0 elements per tile)
  const __bf16* As = A + (size_t)(bm + w * 8 + lr) * K + sx * 8;
  const __bf16* Bs = Bt + (size_t)(bn + w * 8 + lr) * K + sx * 8;

  f32x4 acc[8][4] = {};

  auto STAGE = [&](int k0, int bsel) {
    const __bf16* ap = As + k0;
    const __bf16* bp = Bs + k0;
    const int dbase = bsel * 16384 + (w << 9);
#pragma unroll
    for (int j = 0; j < 4; j++) {
      gload16(ap + (size_t)(j << 6) * K, &lds[dbase + (j << 12)]);
      gload16(bp + (size_t)(j << 6) * K, &lds[32768 + dbase + (j << 12)]);
    }
  };

  auto COMPUTE = [&](int bsel) {
    const int abase = bsel * 16384 + (wr * 128 + fr) * 64;
    const int bbase = 32768 + bsel * 16384 + (wc * 64 + fr) * 64;
#pragma unroll
    for (int ks = 0; ks < 2; ks++) {
      const int sw = (((ks << 2) | kb) ^ l7) << 3;
      b16x8 av[8], bv[4];
#pragma unroll
      for (int m = 0; m < 8; m++)
        av[m] = *reinterpret_cast<const b16x8*>(&lds[abase + m * 1024 + sw]);
#pragma unroll
      for (int n = 0; n < 4; n++)
        bv[n] = *reinterpret_cast<const b16x8*>(&lds[bbase + n * 1024 + sw]);
#pragma unroll
      for (int m = 0; m < 8; m++)
#pragma unroll
        for (int n = 0; n < 4; n++)
          acc[m][n] = __builtin_amdgcn_mfma_f32_16x16x32_bf16(av[m], bv[n], acc[m][n], 0, 0, 0);
    }
  };

  const int nt = K >> 6;
  int cur = 0;
  STAGE(0, 0);
  __syncthreads();
  for (int tt = 0; tt < nt; tt++) {
    if (tt + 1 < nt) STAGE((tt + 1) << 6, cur ^ 1);
    COMPUTE(cur);
    __syncthreads();
    cur ^= 1;
  }

  // epilogue
  const int r0 = kb * 4;
  const int cc = fr;
#pragma unroll
  for (int m = 0; m < 8; m++) {
#pragma unroll
    for (int n = 0; n < 4; n++) {
      const int col = bn + wc * 64 + n * 16 + cc;
#pragma unroll
      for (int r = 0; r < 4; r++) {
        const int row = bm + wr * 128 + m * 16 + r0 + r;
        float val = acc[m][n][r];
        if constexpr (EPI == 0) {
          val += bias[col];
          if (col < 1024) val = sigmoidf_(val);
          const int which = col >> 9;
          const int c2 = col & 511;
          float* dst = (which == 0) ? f0 : (which == 1) ? f1 : f2;
          dst[(size_t)row * 512 + c2] = val;
        } else if constexpr (EPI == 1) {
          f0[(size_t)row * N + col] = val + bias[col];
        } else if constexpr (EPI == 2) {
          const float xg = val + bias[col];
          const float gel = 0.5f * xg * (1.f + erff(xg * 0.70710678118f));
          h0[(size_t)row * N + col] = (__bf16)gel;
        } else {
          const size_t idx = (size_t)row * N + col;
          f0[idx] = f0[idx] + val + bias[col];
        }
      }
    }
  }
}

// ---------------- attention reductions (all f32, batch 0 only) ----------------
__global__ __launch_bounds__(256) void colsums(const float* __restrict__ q,
                                               const float* __restrict__ k,
                                               float* __restrict__ qsum,
                                               float* __restrict__ ksum) {
  const int t = threadIdx.x;
  const int l0 = blockIdx.x * 256;
  float a0 = 0, a1 = 0, b0 = 0, b1 = 0;
  for (int i = 0; i < 256; i++) {
    const float* qr = q + (size_t)(l0 + i) * 512;
    const float* kr = k + (size_t)(l0 + i) * 512;
    a0 += qr[t]; a1 += qr[t + 256];
    b0 += kr[t]; b1 += kr[t + 256];
  }
  atomicAdd(&qsum[t], a0); atomicAdd(&qsum[t + 256], a1);
  atomicAdd(&ksum[t], b0); atomicAdd(&ksum[t + 256], b1);
}

__global__ __launch_bounds__(256) void rowdots1(const float* __restrict__ q,
                                                const float* __restrict__ k,
                                                const float* __restrict__ qsum,
                                                const float* __restrict__ ksum,
                                                float* __restrict__ si,
                                                float* __restrict__ so) {
  const int lane = threadIdx.x & 63, wv = threadIdx.x >> 6;
  const int l = blockIdx.x * 4 + wv;
  const float* qr = q + (size_t)l * 512;
  const float* kr = k + (size_t)l * 512;
#pragma unroll
  for (int h = 0; h < 8; h++) {
    const int c = h * 64 + lane;
    float p1 = (qr[c] + EPSF) * (ksum[c] + EPSF);
    float p2 = (kr[c] + EPSF) * (qsum[c] + EPSF);
#pragma unroll
    for (int off = 32; off > 0; off >>= 1) { p1 += __shfl_down(p1, off); p2 += __shfl_down(p2, off); }
    if (lane == 0) { si[h * L_SEQ + l] = 1.f / p1; so[h * L_SEQ + l] = 1.f / p2; }
  }
}

__global__ __launch_bounds__(256) void colsums2(const float* __restrict__ q,
                                                const float* __restrict__ k,
                                                const float* __restrict__ si,
                                                const float* __restrict__ so,
                                                float* __restrict__ qsi,
                                                float* __restrict__ kso) {
  const int t = threadIdx.x;
  const int l0 = blockIdx.x * 256;
  const int h0 = t >> 6, h1 = (t + 256) >> 6;
  float a0 = 0, a1 = 0, b0 = 0, b1 = 0;
  for (int i = 0; i < 256; i++) {
    const int l = l0 + i;
    const float* qr = q + (size_t)l * 512;
    const float* kr = k + (size_t)l * 512;
    const float si0 = si[h0 * L_SEQ + l], si1 = si[h1 * L_SEQ + l];
    const float so0 = so[h0 * L_SEQ + l], so1 = so[h1 * L_SEQ + l];
    a0 += qr[t] * si0; a1 += qr[t + 256] * si1;
    b0 += kr[t] * so0; b1 += kr[t + 256] * so1;
  }
  atomicAdd(&qsi[t], a0); atomicAdd(&qsi[t + 256], a1);
  atomicAdd(&kso[t], b0); atomicAdd(&kso[t + 256], b1);
}

__global__ __launch_bounds__(256) void rowdots2(const float* __restrict__ q,
                                                const float* __restrict__ k,
                                                const float* __restrict__ qsi,
                                                const float* __restrict__ kso,
                                                float* __restrict__ salloc,
                                                float* __restrict__ compE,
                                                float* __restrict__ sumexp) {
  __shared__ float part[8];
  if (threadIdx.x < 8) part[threadIdx.x] = 0.f;
  __syncthreads();
  const int lane = threadIdx.x & 63, wv = threadIdx.x >> 6;
  float local[8] = {0, 0, 0, 0, 0, 0, 0, 0};
#pragma unroll 1
  for (int i = 0; i < 8; i++) {
    const int l = blockIdx.x * 32 + wv * 8 + i;
    const float* qr = q + (size_t)l * 512;
    const float* kr = k + (size_t)l * 512;
#pragma unroll
    for (int h = 0; h < 8; h++) {
      const int c = h * 64 + lane;
      float p1 = (qr[c] + EPSF) * (kso[c] + EPSF);
      float p2 = (kr[c] + EPSF) * (qsi[c] + EPSF);
#pragma unroll
      for (int off = 32; off > 0; off >>= 1) { p1 += __shfl_down(p1, off); p2 += __shfl_down(p2, off); }
      if (lane == 0) {
        const float cs = fminf(fmaxf(p2, -1.f), 1.f);
        const float e = expf(cs);
        salloc[h * L_SEQ + l] = sigmoidf_(p1);
        compE[h * L_SEQ + l] = e;
        local[h] += e;
      }
    }
  }
  if (lane == 0) {
#pragma unroll
    for (int h = 0; h < 8; h++) atomicAdd(&part[h], local[h]);
  }
  __syncthreads();
  if (threadIdx.x < 8) atomicAdd(&sumexp[threadIdx.x], part[threadIdx.x]);
}

__global__ __launch_bounds__(256) void kv_kernel(const float* __restrict__ k,
                                                 const float* __restrict__ v,
                                                 const float* __restrict__ compE,
                                                 const float* __restrict__ sumexp,
                                                 float* __restrict__ kvout) {
  const int h = blockIdx.y;
  const int t = threadIdx.x;
  __shared__ float lsK[64 * 64];
  __shared__ float lsV[64 * 64];
  const float Sfac = (float)L_SEQ / sumexp[h];
  const int d = t & 63, mg = t >> 6;
  f32x4 acc4[4] = {};
  for (int sc = 0; sc < 8; sc++) {
    const int l0 = blockIdx.x * 512 + sc * 64;
    __syncthreads();
#pragma unroll
    for (int j = 0; j < 16; j++) {
      const int idx = t + j * 256;
      const int lrr = idx >> 6, c = idx & 63;
      const int l = l0 + lrr;
      const float wgt = compE[h * L_SEQ + l] * Sfac;
      lsK[idx] = k[(size_t)l * 512 + h * 64 + c];
      lsV[idx] = v[(size_t)l * 512 + h * 64 + c] * wgt;
    }
    __syncthreads();
    for (int lrr = 0; lrr < 64; lrr++) {
      const float kd = lsK[lrr * 64 + d];
      const f32x4* lv = reinterpret_cast<const f32x4*>(&lsV[lrr * 64 + mg * 16]);
#pragma unroll
      for (int jj = 0; jj < 4; jj++) acc4[jj] += lv[jj] * kd;
    }
  }
#pragma unroll
  for (int jj = 0; jj < 4; jj++)
#pragma unroll
    for (int e = 0; e < 4; e++)
      atomicAdd(&kvout[h * 4096 + d * 64 + mg * 16 + jj * 4 + e], acc4[jj][e]);
}

__global__ __launch_bounds__(256) void o_kernel(const float* __restrict__ q,
                                                const float* __restrict__ kvin,
                                                const float* __restrict__ si,
                                                const float* __restrict__ sal,
                                                __bf16* __restrict__ o) {
  const int h = blockIdx.y;
  const int l0 = blockIdx.x * 32;
  const int t = threadIdx.x;
  __shared__ float lsKV[64 * 64];
  __shared__ float lsQ[32 * 64];
#pragma unroll
  for (int j = 0; j < 16; j++) lsKV[t + j * 256] = kvin[h * 4096 + t + j * 256];
#pragma unroll
  for (int j = 0; j < 8; j++) {
    const int idx = t + j * 256;
    const int r = idx >> 6, c = idx & 63;
    lsQ[idx] = q[(size_t)(l0 + r) * 512 + h * 64 + c];
  }
  __syncthreads();
  const int m = t & 63, rg = t >> 6;
#pragma unroll 1
  for (int i = 0; i < 8; i++) {
    const int r = rg + i * 4;
    const int l = l0 + r;
    float a = 0.f;
#pragma unroll
    for (int d = 0; d < 64; d++) a += lsQ[r * 64 + d] * lsKV[d * 64 + m];
    const float f = sal[h * L_SEQ + l] * si[h * L_SEQ + l];
    o[(size_t)l * 512 + h * 64 + m] = (__bf16)(a * f);
  }
}

// ---------------------------------------------------------------------------
extern "C" void kernel_launch(void* const* d_in, const int* in_sizes, int n_in,
                              void* d_out, int out_size, void* d_ws, size_t ws_size,
                              hipStream_t stream) {
  const float* x  = (const float*)d_in[0];
  const float* Wq = (const float*)d_in[1];
  const float* bq = (const float*)d_in[2];
  const float* Wk = (const float*)d_in[3];
  const float* bk = (const float*)d_in[4];
  const float* Wv = (const float*)d_in[5];
  const float* bv = (const float*)d_in[6];
  const float* Wo = (const float*)d_in[7];
  const float* bo = (const float*)d_in[8];
  const float* W1 = (const float*)d_in[9];
  const float* b1 = (const float*)d_in[10];
  const float* W2 = (const float*)d_in[11];
  const float* b2 = (const float*)d_in[12];
  const float* g1 = (const float*)d_in[13];
  const float* be1 = (const float*)d_in[14];
  const float* g2 = (const float*)d_in[15];
  const float* be2 = (const float*)d_in[16];
  float* out = (float*)d_out;

  char* ws = (char*)d_ws;
  size_t off = 0;
  auto alloc = [&](size_t bytes) -> char* {
    char* p = ws + off;
    off += (bytes + 255) & ~(size_t)255;
    return p;
  };

  // Region A: attention temporaries, later reused as MLP activation (exact fit)
  char* regA = alloc(134217728);
  __bf16* ln1 = (__bf16*)regA;                       // 16384*512 bf16
  float* qb = (float*)(regA + 16777216);             // 16384*512 f32
  float* kb = (float*)(regA + 50331648);
  float* vb = (float*)(regA + 83886080);
  __bf16* ob = (__bf16*)(regA + 117440512);          // 16384*512 bf16
  __bf16* act = (__bf16*)regA;                       // 32768*2048 bf16

  float* sa = (float*)alloc((size_t)16384 * 512 * 4);
  __bf16* ln2 = (__bf16*)alloc((size_t)32768 * 512 * 2);
  __bf16* Wqkvt = (__bf16*)alloc((size_t)1536 * 512 * 2);
  __bf16* Wot = (__bf16*)alloc((size_t)512 * 512 * 2);
  __bf16* W1t = (__bf16*)alloc((size_t)2048 * 512 * 2);
  __bf16* W2t = (__bf16*)alloc((size_t)512 * 2048 * 2);
  float* biascat = (float*)alloc(1536 * 4);
  float* si = (float*)alloc((size_t)8 * L_SEQ * 4);
  float* so = (float*)alloc((size_t)8 * L_SEQ * 4);
  float* sal = (float*)alloc((size_t)8 * L_SEQ * 4);
  float* compE = (float*)alloc((size_t)8 * L_SEQ * 4);
  float* stats = (float*)alloc(34880 * 4);
  float* qsum = stats;
  float* ksum = stats + 512;
  float* qsi = stats + 1024;
  float* kso = stats + 1536;
  float* sumexp = stats + 2048;
  float* kvbuf = stats + 2112;

  // weights -> bf16 transposed
  convT<<<dim3(16, 16), 256, 0, stream>>>(Wq, Wqkvt, 512, 512);
  convT<<<dim3(16, 16), 256, 0, stream>>>(Wk, Wqkvt + (size_t)512 * 512, 512, 512);
  convT<<<dim3(16, 16), 256, 0, stream>>>(Wv, Wqkvt + (size_t)1024 * 512, 512, 512);
  convT<<<dim3(16, 16), 256, 0, stream>>>(Wo, Wot, 512, 512);
  convT<<<dim3(64, 16), 256, 0, stream>>>(W1, W1t, 512, 2048);
  convT<<<dim3(16, 64), 256, 0, stream>>>(W2, W2t, 2048, 512);
  biascat_k<<<6, 256, 0, stream>>>(bq, bk, bv, biascat);
  zero_k<<<(34880 + 255) / 256, 256, 0, stream>>>(stats, 34880);

  // LN1 (batch 0 only) -> QKV GEMM (sigmoid q,k)
  ln_rows<<<L_SEQ, 128, 0, stream>>>(x, g1, be1, ln1);
  gemm256<0><<<384, 512, 0, stream>>>(ln1, Wqkvt, L_SEQ, 1536, 512,
                                      biascat, qb, nullptr, kb, vb);

  // flow-attention normalization chain
  colsums<<<64, 256, 0, stream>>>(qb, kb, qsum, ksum);
  rowdots1<<<L_SEQ / 4, 256, 0, stream>>>(qb, kb, qsum, ksum, si, so);
  colsums2<<<64, 256, 0, stream>>>(qb, kb, si, so, qsi, kso);
  rowdots2<<<L_SEQ / 32, 256, 0, stream>>>(qb, kb, qsi, kso, sal, compE, sumexp);
  kv_kernel<<<dim3(32, 8), 256, 0, stream>>>(kb, vb, compE, sumexp, kvbuf);
  o_kernel<<<dim3(L_SEQ / 32, 8), 256, 0, stream>>>(qb, kvbuf, si, sal, ob);

  // sa = o @ Wo + bo
  gemm256<1><<<128, 512, 0, stream>>>(ob, Wot, L_SEQ, 512, 512,
                                      bo, sa, nullptr, nullptr, nullptr);

  // x2 = x + sa (broadcast over batch) -> d_out; ln2 = LN(x2)
  x2ln2_k<<<2 * L_SEQ, 128, 0, stream>>>(x, sa, g2, be2, out, ln2);

  // MLP: act = gelu(ln2 @ W1 + b1);  d_out += act @ W2 + b2
  gemm256<2><<<1024, 512, 0, stream>>>(ln2, W1t, 2 * L_SEQ, 2048, 512,
                                       b1, nullptr, act, nullptr, nullptr);
  gemm256<3><<<256, 512, 0, stream>>>(act, W2t, 2 * L_SEQ, 512, 2048,
                                      b2, out, nullptr, nullptr, nullptr);
}

// Round 3
// 674.187 us; speedup vs baseline: 1.0835x; 1.0038x over previous
//
#include <hip/hip_runtime.h>
#include <hip/hip_bf16.h>
#include <cstdint>
#include <cstddef>

// ---------------------------------------------------------------------------
// FlowformerLayer: LN1 -> flow-attention(batch0) -> +res -> LN2 -> MLP -> +res
// B=2, L=16384, D=512, H=8, DH=64, F=2048
// GEMMs: 256x256 tile, BK=64, 8 waves, 8-phase schedule (4 phases/K-tile),
//        counted vmcnt (T4), setprio around MFMA (T5), XOR-swizzled LDS (T2),
//        XCD-aware block swizzle (T1).
// Region-safety ledger (race-freedom):
//   consumption (into regs): A{0,2} after q2, A{1,3} after q3, B after q2.
//   stage rule: q0(s):B01(s+1) q1(s):B23(s+1) q2(s):A13(s+1) q3(s):A02(s+2)
//   -> every stage targets a region whose last reader finished >=1 barrier ago.
//   waits: vmcnt(4) at q0 (protects q1's A13) and q3 (protects next q0's
//   A02+B), tail: vmcnt(2)/(0). FIFO ledger verified for prologue+steady+tail.
// ---------------------------------------------------------------------------

#define L_SEQ 16384
#define EPSF 1e-6f

typedef __bf16 b16x8 __attribute__((ext_vector_type(8)));
typedef __bf16 b16x4 __attribute__((ext_vector_type(4)));
typedef float  f32x4 __attribute__((ext_vector_type(4)));

#define FENCE() asm volatile("" ::: "memory")
#define BARF()  { FENCE(); __builtin_amdgcn_s_barrier(); FENCE(); }
#define WAITV(n) asm volatile("s_waitcnt vmcnt(" #n ")" ::: "memory")

__device__ __forceinline__ void gload16(const void* g, void* l) {
  __builtin_amdgcn_global_load_lds((const __attribute__((address_space(1))) void*)g,
                                   (__attribute__((address_space(3))) void*)l, 16, 0, 0);
}

__device__ __forceinline__ float sigmoidf_(float x) { return 1.f / (1.f + __expf(-x)); }

// ---------------- weight convert + transpose: dst[n*K+k] = bf16(src[k*N+n])
__global__ __launch_bounds__(256) void convT(const float* __restrict__ src,
                                             __bf16* __restrict__ dst, int K, int N) {
  __shared__ float tile[32][33];
  const int k0 = blockIdx.y * 32, n0 = blockIdx.x * 32;
  const int tx = threadIdx.x & 31, ty = threadIdx.x >> 5;  // 32 x 8
#pragma unroll
  for (int i = 0; i < 32; i += 8) tile[ty + i][tx] = src[(size_t)(k0 + ty + i) * N + n0 + tx];
  __syncthreads();
#pragma unroll
  for (int i = 0; i < 32; i += 8)
    dst[(size_t)(n0 + ty + i) * K + k0 + tx] = (__bf16)tile[tx][ty + i];
}

__global__ __launch_bounds__(256) void biascat_k(const float* __restrict__ bq,
                                                 const float* __restrict__ bk,
                                                 const float* __restrict__ bv,
                                                 float* __restrict__ bc) {
  int i = blockIdx.x * 256 + threadIdx.x;  // 1536 total
  bc[i] = (i < 512) ? bq[i] : (i < 1024) ? bk[i - 512] : bv[i - 1024];
}

__global__ __launch_bounds__(256) void zero_k(float* __restrict__ p, int n) {
  int i = blockIdx.x * 256 + threadIdx.x;
  if (i < n) p[i] = 0.f;
}

// ---------------- LayerNorm over D=512, one row per block (128 thr x float4)
__global__ __launch_bounds__(128) void ln_rows(const float* __restrict__ x,
                                               const float* __restrict__ g,
                                               const float* __restrict__ be,
                                               __bf16* __restrict__ out) {
  const int row = blockIdx.x, t = threadIdx.x;
  const float4 xv = reinterpret_cast<const float4*>(x + (size_t)row * 512)[t];
  float s = xv.x + xv.y + xv.z + xv.w;
  float s2 = xv.x * xv.x + xv.y * xv.y + xv.z * xv.z + xv.w * xv.w;
#pragma unroll
  for (int off = 32; off > 0; off >>= 1) { s += __shfl_down(s, off); s2 += __shfl_down(s2, off); }
  __shared__ float red[4];
  if ((t & 63) == 0) { red[(t >> 6) * 2] = s; red[(t >> 6) * 2 + 1] = s2; }
  __syncthreads();
  const float S = red[0] + red[2], S2 = red[1] + red[3];
  const float mean = S * (1.f / 512.f);
  const float var = S2 * (1.f / 512.f) - mean * mean;
  const float inv = rsqrtf(var + 1e-5f);
  const float4 gv = reinterpret_cast<const float4*>(g)[t];
  const float4 bv = reinterpret_cast<const float4*>(be)[t];
  b16x4 o;
  o[0] = (__bf16)((xv.x - mean) * inv * gv.x + bv.x);
  o[1] = (__bf16)((xv.y - mean) * inv * gv.y + bv.y);
  o[2] = (__bf16)((xv.z - mean) * inv * gv.z + bv.z);
  o[3] = (__bf16)((xv.w - mean) * inv * gv.w + bv.w);
  reinterpret_cast<b16x4*>(out + (size_t)row * 512)[t] = o;
}

// ---------------- residual + LayerNorm: x2 = x + sa(broadcast); d_out=x2; ln2=LN(x2)
__global__ __launch_bounds__(128) void x2ln2_k(const float* __restrict__ x,
                                               const float* __restrict__ sa,
                                               const float* __restrict__ g,
                                               const float* __restrict__ be,
                                               float* __restrict__ xout,
                                               __bf16* __restrict__ lnout) {
  const int row = blockIdx.x, t = threadIdx.x;
  const int l = row & (L_SEQ - 1);
  float4 xv = reinterpret_cast<const float4*>(x + (size_t)row * 512)[t];
  const float4 sv = reinterpret_cast<const float4*>(sa + (size_t)l * 512)[t];
  xv.x += sv.x; xv.y += sv.y; xv.z += sv.z; xv.w += sv.w;
  reinterpret_cast<float4*>(xout + (size_t)row * 512)[t] = xv;
  float s = xv.x + xv.y + xv.z + xv.w;
  float s2 = xv.x * xv.x + xv.y * xv.y + xv.z * xv.z + xv.w * xv.w;
#pragma unroll
  for (int off = 32; off > 0; off >>= 1) { s += __shfl_down(s, off); s2 += __shfl_down(s2, off); }
  __shared__ float red[4];
  if ((t & 63) == 0) { red[(t >> 6) * 2] = s; red[(t >> 6) * 2 + 1] = s2; }
  __syncthreads();
  const float S = red[0] + red[2], S2 = red[1] + red[3];
  const float mean = S * (1.f / 512.f);
  const float var = S2 * (1.f / 512.f) - mean * mean;
  const float inv = rsqrtf(var + 1e-5f);
  const float4 gv = reinterpret_cast<const float4*>(g)[t];
  const float4 bv = reinterpret_cast<const float4*>(be)[t];
  b16x4 o;
  o[0] = (__bf16)((xv.x - mean) * inv * gv.x + bv.x);
  o[1] = (__bf16)((xv.y - mean) * inv * gv.y + bv.y);
  o[2] = (__bf16)((xv.z - mean) * inv * gv.z + bv.z);
  o[3] = (__bf16)((xv.w - mean) * inv * gv.w + bv.w);
  reinterpret_cast<b16x4*>(lnout + (size_t)row * 512)[t] = o;
}

// ---------------- GEMM 256x256, 8-phase schedule ----------------
// ds-read subtile macros (into av[]/bv[] locals)
#define DSA(mh, ks)                                                           \
  {                                                                           \
    const int ab = bsel * 16384 + (wr * 128 + (mh) * 64 + fr) * 64;           \
    const int sw = ((((ks) << 2) | kb) ^ l7) << 3;                            \
    av[0] = *reinterpret_cast<const b16x8*>(&lds[ab + sw]);                   \
    av[1] = *reinterpret_cast<const b16x8*>(&lds[ab + 1024 + sw]);            \
    av[2] = *reinterpret_cast<const b16x8*>(&lds[ab + 2048 + sw]);            \
    av[3] = *reinterpret_cast<const b16x8*>(&lds[ab + 3072 + sw]);            \
  }
#define DSB(ks)                                                               \
  {                                                                           \
    const int bb = 32768 + bsel * 16384 + (wc * 64 + fr) * 64;                \
    const int sw = ((((ks) << 2) | kb) ^ l7) << 3;                            \
    bv[0] = *reinterpret_cast<const b16x8*>(&lds[bb + sw]);                   \
    bv[1] = *reinterpret_cast<const b16x8*>(&lds[bb + 1024 + sw]);            \
    bv[2] = *reinterpret_cast<const b16x8*>(&lds[bb + 2048 + sw]);            \
    bv[3] = *reinterpret_cast<const b16x8*>(&lds[bb + 3072 + sw]);            \
  }
#define MM(mh)                                                                \
  __builtin_amdgcn_s_setprio(1);                                              \
  _Pragma("unroll") for (int m = 0; m < 4; m++)                               \
      _Pragma("unroll") for (int n = 0; n < 4; n++) acc[(mh) * 4 + m][n] =    \
      __builtin_amdgcn_mfma_f32_16x16x32_bf16(av[m], bv[n],                   \
                                              acc[(mh) * 4 + m][n], 0, 0, 0); \
  __builtin_amdgcn_s_setprio(0);

// EPI 0: QKV (+biascat, sigmoid cols<1024, scatter f32 -> q/k/v)
// EPI 1: SA  (+bias -> f32, stride N)
// EPI 2: GELU(+bias -> bf16, stride N)
// EPI 3: OUT (f0[row,col] += acc + bias)
template <int EPI>
__global__ __launch_bounds__(512) void gemm256(const __bf16* __restrict__ A,
                                               const __bf16* __restrict__ Bt,
                                               const int M, const int N, const int K,
                                               const float* __restrict__ bias,
                                               float* __restrict__ f0,
                                               __bf16* __restrict__ h0,
                                               float* __restrict__ f1,
                                               float* __restrict__ f2) {
  __shared__ alignas(16) __bf16 lds[65536];  // 128 KB

  // XCD-aware block swizzle (all grids are %8==0)
  const int nwg = gridDim.x;
  const int orig = blockIdx.x;
  const int cpx = nwg >> 3;
  const int wg = (orig & 7) * cpx + (orig >> 3);
  const int gx = N >> 8;
  const int bm = (wg / gx) << 8;
  const int bn = (wg % gx) << 8;

  const int t = threadIdx.x;
  const int w = t >> 6, lane = t & 63;
  const int wr = w >> 2, wc = w & 3;
  const int lr = lane >> 3;                // staging row-in-group 0..7
  const int sx = (lane & 7) ^ lr;          // pre-swizzled source chunk
  const int fr = lane & 15;                // fragment row select
  const int kb = lane >> 4;                // 0..3 (16B chunk within k-step)
  const int l7 = lane & 7;

  // per-lane staging base pointers
  const __bf16* As = A + (size_t)(bm + w * 8 + lr) * K + sx * 8;
  const __bf16* Bs = Bt + (size_t)(bn + w * 8 + lr) * K + sx * 8;

  f32x4 acc[8][4] = {};

  // stage A quarters j0,j1 (rows j*64..j*64+63) of K-tile s
  auto STG_A = [&](int s, int j0, int j1) {
    const __bf16* ap = As + (s << 6);
    const int dbase = (s & 1) * 16384 + (w << 9);
    gload16(ap + (size_t)(j0 << 6) * K, &lds[dbase + (j0 << 12)]);
    gload16(ap + (size_t)(j1 << 6) * K, &lds[dbase + (j1 << 12)]);
  };
  auto STG_B = [&](int s, int j0, int j1) {
    const __bf16* bp = Bs + (s << 6);
    const int dbase = 32768 + (s & 1) * 16384 + (w << 9);
    gload16(bp + (size_t)(j0 << 6) * K, &lds[dbase + (j0 << 12)]);
    gload16(bp + (size_t)(j1 << 6) * K, &lds[dbase + (j1 << 12)]);
  };

  const int nt = K >> 6;

  // prologue: tile0 fully + tile1.A02 ; drain tile0, keep tile1.A02 in flight
  STG_A(0, 0, 2);
  STG_B(0, 0, 1);
  STG_B(0, 2, 3);
  STG_A(0, 1, 3);
  STG_A(1, 0, 2);
  WAITV(2);
  BARF();

  for (int s = 0; s < nt; s++) {
    const int bsel = s & 1;
    b16x8 av[4], bv[4];
    // ---- q0: compute (m0-3 x n0-3, ks0); stage B01(s+1)
    DSA(0, 0);
    DSB(0);
    if (s + 1 < nt) { STG_B(s + 1, 0, 1); WAITV(4); } else { WAITV(0); }
    BARF();
    MM(0);
    BARF();
    // ---- q1: compute (m4-7 x n0-3, ks0); stage B23(s+1)
    DSA(1, 0);
    if (s + 1 < nt) STG_B(s + 1, 2, 3);
    BARF();
    MM(1);
    BARF();
    // ---- q2: compute (m0-3 x n0-3, ks1); stage A13(s+1)
    DSA(0, 1);
    DSB(1);
    if (s + 1 < nt) STG_A(s + 1, 1, 3);
    BARF();
    MM(0);
    BARF();
    // ---- q3: compute (m4-7 x n0-3, ks1); stage A02(s+2)
    DSA(1, 1);
    if (s + 2 < nt) { STG_A(s + 2, 0, 2); WAITV(4); }
    else if (s + 1 < nt) { WAITV(2); }
    BARF();
    MM(1);
    BARF();
  }

  // epilogue
  const int r0 = kb * 4;
  const int cc = fr;
#pragma unroll
  for (int m = 0; m < 8; m++) {
#pragma unroll
    for (int n = 0; n < 4; n++) {
      const int col = bn + wc * 64 + n * 16 + cc;
#pragma unroll
      for (int r = 0; r < 4; r++) {
        const int row = bm + wr * 128 + m * 16 + r0 + r;
        float val = acc[m][n][r];
        if constexpr (EPI == 0) {
          val += bias[col];
          if (col < 1024) val = sigmoidf_(val);
          const int which = col >> 9;
          const int c2 = col & 511;
          float* dst = (which == 0) ? f0 : (which == 1) ? f1 : f2;
          dst[(size_t)row * 512 + c2] = val;
        } else if constexpr (EPI == 1) {
          f0[(size_t)row * N + col] = val + bias[col];
        } else if constexpr (EPI == 2) {
          const float xg = val + bias[col];
          const float gel = 0.5f * xg * (1.f + erff(xg * 0.70710678118f));
          h0[(size_t)row * N + col] = (__bf16)gel;
        } else {
          const size_t idx = (size_t)row * N + col;
          f0[idx] = f0[idx] + val + bias[col];
        }
      }
    }
  }
}

// ---------------- attention reductions (all f32, batch 0 only) ----------------
__global__ __launch_bounds__(256) void colsums(const float* __restrict__ q,
                                               const float* __restrict__ k,
                                               float* __restrict__ qsum,
                                               float* __restrict__ ksum) {
  const int t = threadIdx.x;
  const int l0 = blockIdx.x * 256;
  float a0 = 0, a1 = 0, b0 = 0, b1 = 0;
  for (int i = 0; i < 256; i++) {
    const float* qr = q + (size_t)(l0 + i) * 512;
    const float* kr = k + (size_t)(l0 + i) * 512;
    a0 += qr[t]; a1 += qr[t + 256];
    b0 += kr[t]; b1 += kr[t + 256];
  }
  atomicAdd(&qsum[t], a0); atomicAdd(&qsum[t + 256], a1);
  atomicAdd(&ksum[t], b0); atomicAdd(&ksum[t + 256], b1);
}

__global__ __launch_bounds__(256) void rowdots1(const float* __restrict__ q,
                                                const float* __restrict__ k,
                                                const float* __restrict__ qsum,
                                                const float* __restrict__ ksum,
                                                float* __restrict__ si,
                                                float* __restrict__ so) {
  const int lane = threadIdx.x & 63, wv = threadIdx.x >> 6;
  const int l = blockIdx.x * 4 + wv;
  const float* qr = q + (size_t)l * 512;
  const float* kr = k + (size_t)l * 512;
#pragma unroll
  for (int h = 0; h < 8; h++) {
    const int c = h * 64 + lane;
    float p1 = (qr[c] + EPSF) * (ksum[c] + EPSF);
    float p2 = (kr[c] + EPSF) * (qsum[c] + EPSF);
#pragma unroll
    for (int off = 32; off > 0; off >>= 1) { p1 += __shfl_down(p1, off); p2 += __shfl_down(p2, off); }
    if (lane == 0) { si[h * L_SEQ + l] = 1.f / p1; so[h * L_SEQ + l] = 1.f / p2; }
  }
}

__global__ __launch_bounds__(256) void colsums2(const float* __restrict__ q,
                                                const float* __restrict__ k,
                                                const float* __restrict__ si,
                                                const float* __restrict__ so,
                                                float* __restrict__ qsi,
                                                float* __restrict__ kso) {
  const int t = threadIdx.x;
  const int l0 = blockIdx.x * 256;
  const int h0 = t >> 6, h1 = (t + 256) >> 6;
  float a0 = 0, a1 = 0, b0 = 0, b1 = 0;
  for (int i = 0; i < 256; i++) {
    const int l = l0 + i;
    const float* qr = q + (size_t)l * 512;
    const float* kr = k + (size_t)l * 512;
    const float si0 = si[h0 * L_SEQ + l], si1 = si[h1 * L_SEQ + l];
    const float so0 = so[h0 * L_SEQ + l], so1 = so[h1 * L_SEQ + l];
    a0 += qr[t] * si0; a1 += qr[t + 256] * si1;
    b0 += kr[t] * so0; b1 += kr[t + 256] * so1;
  }
  atomicAdd(&qsi[t], a0); atomicAdd(&qsi[t + 256], a1);
  atomicAdd(&kso[t], b0); atomicAdd(&kso[t + 256], b1);
}

__global__ __launch_bounds__(256) void rowdots2(const float* __restrict__ q,
                                                const float* __restrict__ k,
                                                const float* __restrict__ qsi,
                                                const float* __restrict__ kso,
                                                float* __restrict__ salloc,
                                                float* __restrict__ compE,
                                                float* __restrict__ sumexp) {
  __shared__ float part[8];
  if (threadIdx.x < 8) part[threadIdx.x] = 0.f;
  __syncthreads();
  const int lane = threadIdx.x & 63, wv = threadIdx.x >> 6;
  float local[8] = {0, 0, 0, 0, 0, 0, 0, 0};
#pragma unroll 1
  for (int i = 0; i < 8; i++) {
    const int l = blockIdx.x * 32 + wv * 8 + i;
    const float* qr = q + (size_t)l * 512;
    const float* kr = k + (size_t)l * 512;
#pragma unroll
    for (int h = 0; h < 8; h++) {
      const int c = h * 64 + lane;
      float p1 = (qr[c] + EPSF) * (kso[c] + EPSF);
      float p2 = (kr[c] + EPSF) * (qsi[c] + EPSF);
#pragma unroll
      for (int off = 32; off > 0; off >>= 1) { p1 += __shfl_down(p1, off); p2 += __shfl_down(p2, off); }
      if (lane == 0) {
        const float cs = fminf(fmaxf(p2, -1.f), 1.f);
        const float e = expf(cs);
        salloc[h * L_SEQ + l] = sigmoidf_(p1);
        compE[h * L_SEQ + l] = e;
        local[h] += e;
      }
    }
  }
  if (lane == 0) {
#pragma unroll
    for (int h = 0; h < 8; h++) atomicAdd(&part[h], local[h]);
  }
  __syncthreads();
  if (threadIdx.x < 8) atomicAdd(&sumexp[threadIdx.x], part[threadIdx.x]);
}

__global__ __launch_bounds__(256) void kv_kernel(const float* __restrict__ k,
                                                 const float* __restrict__ v,
                                                 const float* __restrict__ compE,
                                                 const float* __restrict__ sumexp,
                                                 float* __restrict__ kvout) {
  const int h = blockIdx.y;
  const int t = threadIdx.x;
  __shared__ float lsK[64 * 64];
  __shared__ float lsV[64 * 64];
  const float Sfac = (float)L_SEQ / sumexp[h];
  const int d = t & 63, mg = t >> 6;
  f32x4 acc4[4] = {};
  for (int sc = 0; sc < 8; sc++) {
    const int l0 = blockIdx.x * 512 + sc * 64;
    __syncthreads();
#pragma unroll
    for (int j = 0; j < 16; j++) {
      const int idx = t + j * 256;
      const int lrr = idx >> 6, c = idx & 63;
      const int l = l0 + lrr;
      const float wgt = compE[h * L_SEQ + l] * Sfac;
      lsK[idx] = k[(size_t)l * 512 + h * 64 + c];
      lsV[idx] = v[(size_t)l * 512 + h * 64 + c] * wgt;
    }
    __syncthreads();
    for (int lrr = 0; lrr < 64; lrr++) {
      const float kd = lsK[lrr * 64 + d];
      const f32x4* lv = reinterpret_cast<const f32x4*>(&lsV[lrr * 64 + mg * 16]);
#pragma unroll
      for (int jj = 0; jj < 4; jj++) acc4[jj] += lv[jj] * kd;
    }
  }
#pragma unroll
  for (int jj = 0; jj < 4; jj++)
#pragma unroll
    for (int e = 0; e < 4; e++)
      atomicAdd(&kvout[h * 4096 + d * 64 + mg * 16 + jj * 4 + e], acc4[jj][e]);
}

__global__ __launch_bounds__(256) void o_kernel(const float* __restrict__ q,
                                                const float* __restrict__ kvin,
                                                const float* __restrict__ si,
                                                const float* __restrict__ sal,
                                                __bf16* __restrict__ o) {
  const int h = blockIdx.y;
  const int l0 = blockIdx.x * 32;
  const int t = threadIdx.x;
  __shared__ float lsKV[64 * 64];
  __shared__ float lsQ[32 * 64];
#pragma unroll
  for (int j = 0; j < 16; j++) lsKV[t + j * 256] = kvin[h * 4096 + t + j * 256];
#pragma unroll
  for (int j = 0; j < 8; j++) {
    const int idx = t + j * 256;
    const int r = idx >> 6, c = idx & 63;
    lsQ[idx] = q[(size_t)(l0 + r) * 512 + h * 64 + c];
  }
  __syncthreads();
  const int m = t & 63, rg = t >> 6;
#pragma unroll 1
  for (int i = 0; i < 8; i++) {
    const int r = rg + i * 4;
    const int l = l0 + r;
    float a = 0.f;
#pragma unroll
    for (int d = 0; d < 64; d++) a += lsQ[r * 64 + d] * lsKV[d * 64 + m];
    const float f = sal[h * L_SEQ + l] * si[h * L_SEQ + l];
    o[(size_t)l * 512 + h * 64 + m] = (__bf16)(a * f);
  }
}

// ---------------------------------------------------------------------------
extern "C" void kernel_launch(void* const* d_in, const int* in_sizes, int n_in,
                              void* d_out, int out_size, void* d_ws, size_t ws_size,
                              hipStream_t stream) {
  const float* x  = (const float*)d_in[0];
  const float* Wq = (const float*)d_in[1];
  const float* bq = (const float*)d_in[2];
  const float* Wk = (const float*)d_in[3];
  const float* bk = (const float*)d_in[4];
  const float* Wv = (const float*)d_in[5];
  const float* bv = (const float*)d_in[6];
  const float* Wo = (const float*)d_in[7];
  const float* bo = (const float*)d_in[8];
  const float* W1 = (const float*)d_in[9];
  const float* b1 = (const float*)d_in[10];
  const float* W2 = (const float*)d_in[11];
  const float* b2 = (const float*)d_in[12];
  const float* g1 = (const float*)d_in[13];
  const float* be1 = (const float*)d_in[14];
  const float* g2 = (const float*)d_in[15];
  const float* be2 = (const float*)d_in[16];
  float* out = (float*)d_out;

  char* ws = (char*)d_ws;
  size_t off = 0;
  auto alloc = [&](size_t bytes) -> char* {
    char* p = ws + off;
    off += (bytes + 255) & ~(size_t)255;
    return p;
  };

  // Region A: attention temporaries, later reused as MLP activation (exact fit)
  char* regA = alloc(134217728);
  __bf16* ln1 = (__bf16*)regA;                       // 16384*512 bf16
  float* qb = (float*)(regA + 16777216);             // 16384*512 f32
  float* kb = (float*)(regA + 50331648);
  float* vb = (float*)(regA + 83886080);
  __bf16* ob = (__bf16*)(regA + 117440512);          // 16384*512 bf16
  __bf16* act = (__bf16*)regA;                       // 32768*2048 bf16

  float* sa = (float*)alloc((size_t)16384 * 512 * 4);
  __bf16* ln2 = (__bf16*)alloc((size_t)32768 * 512 * 2);
  __bf16* Wqkvt = (__bf16*)alloc((size_t)1536 * 512 * 2);
  __bf16* Wot = (__bf16*)alloc((size_t)512 * 512 * 2);
  __bf16* W1t = (__bf16*)alloc((size_t)2048 * 512 * 2);
  __bf16* W2t = (__bf16*)alloc((size_t)512 * 2048 * 2);
  float* biascat = (float*)alloc(1536 * 4);
  float* si = (float*)alloc((size_t)8 * L_SEQ * 4);
  float* so = (float*)alloc((size_t)8 * L_SEQ * 4);
  float* sal = (float*)alloc((size_t)8 * L_SEQ * 4);
  float* compE = (float*)alloc((size_t)8 * L_SEQ * 4);
  float* stats = (float*)alloc(34880 * 4);
  float* qsum = stats;
  float* ksum = stats + 512;
  float* qsi = stats + 1024;
  float* kso = stats + 1536;
  float* sumexp = stats + 2048;
  float* kvbuf = stats + 2112;

  // weights -> bf16 transposed
  convT<<<dim3(16, 16), 256, 0, stream>>>(Wq, Wqkvt, 512, 512);
  convT<<<dim3(16, 16), 256, 0, stream>>>(Wk, Wqkvt + (size_t)512 * 512, 512, 512);
  convT<<<dim3(16, 16), 256, 0, stream>>>(Wv, Wqkvt + (size_t)1024 * 512, 512, 512);
  convT<<<dim3(16, 16), 256, 0, stream>>>(Wo, Wot, 512, 512);
  convT<<<dim3(64, 16), 256, 0, stream>>>(W1, W1t, 512, 2048);
  convT<<<dim3(16, 64), 256, 0, stream>>>(W2, W2t, 2048, 512);
  biascat_k<<<6, 256, 0, stream>>>(bq, bk, bv, biascat);
  zero_k<<<(34880 + 255) / 256, 256, 0, stream>>>(stats, 34880);

  // LN1 (batch 0 only) -> QKV GEMM (sigmoid q,k)
  ln_rows<<<L_SEQ, 128, 0, stream>>>(x, g1, be1, ln1);
  gemm256<0><<<384, 512, 0, stream>>>(ln1, Wqkvt, L_SEQ, 1536, 512,
                                      biascat, qb, nullptr, kb, vb);

  // flow-attention normalization chain
  colsums<<<64, 256, 0, stream>>>(qb, kb, qsum, ksum);
  rowdots1<<<L_SEQ / 4, 256, 0, stream>>>(qb, kb, qsum, ksum, si, so);
  colsums2<<<64, 256, 0, stream>>>(qb, kb, si, so, qsi, kso);
  rowdots2<<<L_SEQ / 32, 256, 0, stream>>>(qb, kb, qsi, kso, sal, compE, sumexp);
  kv_kernel<<<dim3(32, 8), 256, 0, stream>>>(kb, vb, compE, sumexp, kvbuf);
  o_kernel<<<dim3(L_SEQ / 32, 8), 256, 0, stream>>>(qb, kvbuf, si, sal, ob);

  // sa = o @ Wo + bo
  gemm256<1><<<128, 512, 0, stream>>>(ob, Wot, L_SEQ, 512, 512,
                                      bo, sa, nullptr, nullptr, nullptr);

  // x2 = x + sa (broadcast over batch) -> d_out; ln2 = LN(x2)
  x2ln2_k<<<2 * L_SEQ, 128, 0, stream>>>(x, sa, g2, be2, out, ln2);

  // MLP: act = gelu(ln2 @ W1 + b1);  d_out += act @ W2 + b2
  gemm256<2><<<1024, 512, 0, stream>>>(ln2, W1t, 2 * L_SEQ, 2048, 512,
                                       b1, nullptr, act, nullptr, nullptr);
  gemm256<3><<<256, 512, 0, stream>>>(act, W2t, 2 * L_SEQ, 512, 2048,
                                      b2, out, nullptr, nullptr, nullptr);
}

// Round 4
// 638.307 us; speedup vs baseline: 1.1444x; 1.0562x over previous
//
#include <hip/hip_runtime.h>
#include <hip/hip_bf16.h>
#include <cstdint>
#include <cstddef>

// ---------------------------------------------------------------------------
// FlowformerLayer: LN1 -> flow-attention(batch0) -> +res -> LN2 -> MLP -> +res
// B=2, L=16384, D=512, H=8, DH=64, F=2048
// GEMMs: 256x256 tile, BK=64, 8 waves, 8-phase schedule, counted vmcnt,
//        setprio, XOR-swizzled LDS, XCD swizzle. Wo uses split-K x2.
// Attention chain fused to 3 passes (pass1, kv, o) over bf16 q/k + f32 v.
// ---------------------------------------------------------------------------

#define L_SEQ 16384
#define EPSF 1e-6f

typedef __bf16 b16x8 __attribute__((ext_vector_type(8)));
typedef __bf16 b16x4 __attribute__((ext_vector_type(4)));
typedef float  f32x4 __attribute__((ext_vector_type(4)));

#define FENCE() asm volatile("" ::: "memory")
#define BARF()  { FENCE(); __builtin_amdgcn_s_barrier(); FENCE(); }
#define WAITV(n) asm volatile("s_waitcnt vmcnt(" #n ")" ::: "memory")

__device__ __forceinline__ void gload16(const void* g, void* l) {
  __builtin_amdgcn_global_load_lds((const __attribute__((address_space(1))) void*)g,
                                   (__attribute__((address_space(3))) void*)l, 16, 0, 0);
}

__device__ __forceinline__ float sigmoidf_(float x) { return 1.f / (1.f + __expf(-x)); }

// ---------------- weight convert + transpose: dst[n*K+k] = bf16(src[k*N+n])
__global__ __launch_bounds__(256) void convT(const float* __restrict__ src,
                                             __bf16* __restrict__ dst, int K, int N) {
  __shared__ float tile[32][33];
  const int k0 = blockIdx.y * 32, n0 = blockIdx.x * 32;
  const int tx = threadIdx.x & 31, ty = threadIdx.x >> 5;  // 32 x 8
#pragma unroll
  for (int i = 0; i < 32; i += 8) tile[ty + i][tx] = src[(size_t)(k0 + ty + i) * N + n0 + tx];
  __syncthreads();
#pragma unroll
  for (int i = 0; i < 32; i += 8)
    dst[(size_t)(n0 + ty + i) * K + k0 + tx] = (__bf16)tile[tx][ty + i];
}

__global__ __launch_bounds__(256) void biascat_k(const float* __restrict__ bq,
                                                 const float* __restrict__ bk,
                                                 const float* __restrict__ bv,
                                                 float* __restrict__ bc) {
  int i = blockIdx.x * 256 + threadIdx.x;  // 1536 total
  bc[i] = (i < 512) ? bq[i] : (i < 1024) ? bk[i - 512] : bv[i - 1024];
}

__global__ __launch_bounds__(256) void zero_k(float* __restrict__ p, int n) {
  int i = blockIdx.x * 256 + threadIdx.x;
  if (i < n) p[i] = 0.f;
}

// ---------------- LayerNorm over D=512, one row per block (128 thr x float4)
__global__ __launch_bounds__(128) void ln_rows(const float* __restrict__ x,
                                               const float* __restrict__ g,
                                               const float* __restrict__ be,
                                               __bf16* __restrict__ out) {
  const int row = blockIdx.x, t = threadIdx.x;
  const float4 xv = reinterpret_cast<const float4*>(x + (size_t)row * 512)[t];
  float s = xv.x + xv.y + xv.z + xv.w;
  float s2 = xv.x * xv.x + xv.y * xv.y + xv.z * xv.z + xv.w * xv.w;
#pragma unroll
  for (int off = 32; off > 0; off >>= 1) { s += __shfl_down(s, off); s2 += __shfl_down(s2, off); }
  __shared__ float red[4];
  if ((t & 63) == 0) { red[(t >> 6) * 2] = s; red[(t >> 6) * 2 + 1] = s2; }
  __syncthreads();
  const float S = red[0] + red[2], S2 = red[1] + red[3];
  const float mean = S * (1.f / 512.f);
  const float var = S2 * (1.f / 512.f) - mean * mean;
  const float inv = rsqrtf(var + 1e-5f);
  const float4 gv = reinterpret_cast<const float4*>(g)[t];
  const float4 bv = reinterpret_cast<const float4*>(be)[t];
  b16x4 o;
  o[0] = (__bf16)((xv.x - mean) * inv * gv.x + bv.x);
  o[1] = (__bf16)((xv.y - mean) * inv * gv.y + bv.y);
  o[2] = (__bf16)((xv.z - mean) * inv * gv.z + bv.z);
  o[3] = (__bf16)((xv.w - mean) * inv * gv.w + bv.w);
  reinterpret_cast<b16x4*>(out + (size_t)row * 512)[t] = o;
}

// ---------------- x2 = x + sa0 + sa1 + bo (broadcast); d_out=x2; ln2=LN(x2)
__global__ __launch_bounds__(128) void x2ln2_k(const float* __restrict__ x,
                                               const float* __restrict__ sa0,
                                               const float* __restrict__ sa1,
                                               const float* __restrict__ bo,
                                               const float* __restrict__ g,
                                               const float* __restrict__ be,
                                               float* __restrict__ xout,
                                               __bf16* __restrict__ lnout) {
  const int row = blockIdx.x, t = threadIdx.x;
  const int l = row & (L_SEQ - 1);
  float4 xv = reinterpret_cast<const float4*>(x + (size_t)row * 512)[t];
  const float4 s0 = reinterpret_cast<const float4*>(sa0 + (size_t)l * 512)[t];
  const float4 s1 = reinterpret_cast<const float4*>(sa1 + (size_t)l * 512)[t];
  const float4 bb = reinterpret_cast<const float4*>(bo)[t];
  xv.x += s0.x + s1.x + bb.x; xv.y += s0.y + s1.y + bb.y;
  xv.z += s0.z + s1.z + bb.z; xv.w += s0.w + s1.w + bb.w;
  reinterpret_cast<float4*>(xout + (size_t)row * 512)[t] = xv;
  float s = xv.x + xv.y + xv.z + xv.w;
  float s2 = xv.x * xv.x + xv.y * xv.y + xv.z * xv.z + xv.w * xv.w;
#pragma unroll
  for (int off = 32; off > 0; off >>= 1) { s += __shfl_down(s, off); s2 += __shfl_down(s2, off); }
  __shared__ float red[4];
  if ((t & 63) == 0) { red[(t >> 6) * 2] = s; red[(t >> 6) * 2 + 1] = s2; }
  __syncthreads();
  const float S = red[0] + red[2], S2 = red[1] + red[3];
  const float mean = S * (1.f / 512.f);
  const float var = S2 * (1.f / 512.f) - mean * mean;
  const float inv = rsqrtf(var + 1e-5f);
  const float4 gv = reinterpret_cast<const float4*>(g)[t];
  const float4 bv = reinterpret_cast<const float4*>(be)[t];
  b16x4 o;
  o[0] = (__bf16)((xv.x - mean) * inv * gv.x + bv.x);
  o[1] = (__bf16)((xv.y - mean) * inv * gv.y + bv.y);
  o[2] = (__bf16)((xv.z - mean) * inv * gv.z + bv.z);
  o[3] = (__bf16)((xv.w - mean) * inv * gv.w + bv.w);
  reinterpret_cast<b16x4*>(lnout + (size_t)row * 512)[t] = o;
}

// ---------------- GEMM 256x256, 8-phase schedule ----------------
#define DSA(mh, ks)                                                           \
  {                                                                           \
    const int ab = bsel * 16384 + (wr * 128 + (mh) * 64 + fr) * 64;           \
    const int sw = ((((ks) << 2) | kb) ^ l7) << 3;                            \
    av[0] = *reinterpret_cast<const b16x8*>(&lds[ab + sw]);                   \
    av[1] = *reinterpret_cast<const b16x8*>(&lds[ab + 1024 + sw]);            \
    av[2] = *reinterpret_cast<const b16x8*>(&lds[ab + 2048 + sw]);            \
    av[3] = *reinterpret_cast<const b16x8*>(&lds[ab + 3072 + sw]);            \
  }
#define DSB(ks)                                                               \
  {                                                                           \
    const int bb = 32768 + bsel * 16384 + (wc * 64 + fr) * 64;                \
    const int sw = ((((ks) << 2) | kb) ^ l7) << 3;                            \
    bv[0] = *reinterpret_cast<const b16x8*>(&lds[bb + sw]);                   \
    bv[1] = *reinterpret_cast<const b16x8*>(&lds[bb + 1024 + sw]);            \
    bv[2] = *reinterpret_cast<const b16x8*>(&lds[bb + 2048 + sw]);            \
    bv[3] = *reinterpret_cast<const b16x8*>(&lds[bb + 3072 + sw]);            \
  }
#define MM(mh)                                                                \
  __builtin_amdgcn_s_setprio(1);                                              \
  _Pragma("unroll") for (int m = 0; m < 4; m++)                               \
      _Pragma("unroll") for (int n = 0; n < 4; n++) acc[(mh) * 4 + m][n] =    \
      __builtin_amdgcn_mfma_f32_16x16x32_bf16(av[m], bv[n],                   \
                                              acc[(mh) * 4 + m][n], 0, 0, 0); \
  __builtin_amdgcn_s_setprio(0);

// EPI 0: QKV (+biascat, sigmoid q/k -> bf16 h0/h1 + column sums f1/f2; v -> f0)
// EPI 1: SA  (val only -> f0, split-K via blockIdx.y when KSPL)
// EPI 2: GELU(+bias -> bf16 h0, stride N)
// EPI 3: OUT (f0[row,col] += acc + bias)
template <int EPI, int KSPL>
__global__ __launch_bounds__(512) void gemm256(const __bf16* __restrict__ A,
                                               const __bf16* __restrict__ Bt,
                                               const int M, const int N, const int K,
                                               const float* __restrict__ bias,
                                               float* __restrict__ f0,
                                               __bf16* __restrict__ h0,
                                               __bf16* __restrict__ h1,
                                               float* __restrict__ f1,
                                               float* __restrict__ f2) {
  __shared__ alignas(16) __bf16 lds[65536];  // 128 KB

  if constexpr (KSPL) {
    const int z = blockIdx.y;
    A += (size_t)z * (K >> 1);
    Bt += (size_t)z * (K >> 1);
    f0 += (size_t)z * ((size_t)M * N);
  }
  const int nt = KSPL ? (K >> 7) : (K >> 6);

  // XCD-aware block swizzle (all x-grids are %8==0)
  const int nwg = gridDim.x;
  const int orig = blockIdx.x;
  const int cpx = nwg >> 3;
  const int wg = (orig & 7) * cpx + (orig >> 3);
  const int gx = N >> 8;
  const int bm = (wg / gx) << 8;
  const int bn = (wg % gx) << 8;

  const int t = threadIdx.x;
  const int w = t >> 6, lane = t & 63;
  const int wr = w >> 2, wc = w & 3;
  const int lr = lane >> 3;                // staging row-in-group 0..7
  const int sx = (lane & 7) ^ lr;          // pre-swizzled source chunk
  const int fr = lane & 15;                // fragment row select
  const int kb = lane >> 4;                // 0..3 (16B chunk within k-step)
  const int l7 = lane & 7;

  const __bf16* As = A + (size_t)(bm + w * 8 + lr) * K + sx * 8;
  const __bf16* Bs = Bt + (size_t)(bn + w * 8 + lr) * K + sx * 8;

  f32x4 acc[8][4] = {};

  auto STG_A = [&](int s, int j0, int j1) {
    const __bf16* ap = As + (s << 6);
    const int dbase = (s & 1) * 16384 + (w << 9);
    gload16(ap + (size_t)(j0 << 6) * K, &lds[dbase + (j0 << 12)]);
    gload16(ap + (size_t)(j1 << 6) * K, &lds[dbase + (j1 << 12)]);
  };
  auto STG_B = [&](int s, int j0, int j1) {
    const __bf16* bp = Bs + (s << 6);
    const int dbase = 32768 + (s & 1) * 16384 + (w << 9);
    gload16(bp + (size_t)(j0 << 6) * K, &lds[dbase + (j0 << 12)]);
    gload16(bp + (size_t)(j1 << 6) * K, &lds[dbase + (j1 << 12)]);
  };

  // prologue: tile0 fully + tile1.A02; drain tile0, keep tile1.A02 in flight
  STG_A(0, 0, 2);
  STG_B(0, 0, 1);
  STG_B(0, 2, 3);
  STG_A(0, 1, 3);
  STG_A(1, 0, 2);
  WAITV(2);
  BARF();

  for (int s = 0; s < nt; s++) {
    const int bsel = s & 1;
    b16x8 av[4], bv[4];
    // q0
    DSA(0, 0);
    DSB(0);
    if (s + 1 < nt) { STG_B(s + 1, 0, 1); WAITV(4); } else { WAITV(0); }
    BARF();
    MM(0);
    BARF();
    // q1
    DSA(1, 0);
    if (s + 1 < nt) STG_B(s + 1, 2, 3);
    BARF();
    MM(1);
    BARF();
    // q2
    DSA(0, 1);
    DSB(1);
    if (s + 1 < nt) STG_A(s + 1, 1, 3);
    BARF();
    MM(0);
    BARF();
    // q3
    DSA(1, 1);
    if (s + 2 < nt) { STG_A(s + 2, 0, 2); WAITV(4); }
    else if (s + 1 < nt) { WAITV(2); }
    BARF();
    MM(1);
    BARF();
  }

  // epilogue
  const int r0 = kb * 4;
  const int cc = fr;
  if constexpr (EPI == 0) {
    const int which = bn >> 9;  // 0=q, 1=k, 2=v (uniform per block)
    float cs[4] = {0.f, 0.f, 0.f, 0.f};
#pragma unroll
    for (int m = 0; m < 8; m++) {
#pragma unroll
      for (int n = 0; n < 4; n++) {
        const int col = bn + wc * 64 + n * 16 + cc;
        const int c2 = col & 511;
#pragma unroll
        for (int r = 0; r < 4; r++) {
          const int row = bm + wr * 128 + m * 16 + r0 + r;
          float val = acc[m][n][r] + bias[col];
          if (which < 2) {
            val = sigmoidf_(val);
            cs[n] += val;
            ((which == 0) ? h0 : h1)[(size_t)row * 512 + c2] = (__bf16)val;
          } else {
            f0[(size_t)row * 512 + c2] = val;
          }
        }
      }
    }
    if (which < 2) {
      float* sums = (which == 0) ? f1 : f2;
#pragma unroll
      for (int n = 0; n < 4; n++) {
        float s = cs[n];
        s += __shfl_xor(s, 16);
        s += __shfl_xor(s, 32);
        if (kb == 0) atomicAdd(&sums[(bn & 511) + wc * 64 + n * 16 + cc], s);
      }
    }
  } else {
#pragma unroll
    for (int m = 0; m < 8; m++) {
#pragma unroll
      for (int n = 0; n < 4; n++) {
        const int col = bn + wc * 64 + n * 16 + cc;
#pragma unroll
        for (int r = 0; r < 4; r++) {
          const int row = bm + wr * 128 + m * 16 + r0 + r;
          float val = acc[m][n][r];
          if constexpr (EPI == 1) {
            f0[(size_t)row * N + col] = val;
          } else if constexpr (EPI == 2) {
            const float xg = val + bias[col];
            const float gel = 0.5f * xg * (1.f + erff(xg * 0.70710678118f));
            h0[(size_t)row * N + col] = (__bf16)gel;
          } else {
            const size_t idx = (size_t)row * N + col;
            f0[idx] = f0[idx] + val + bias[col];
          }
        }
      }
    }
  }
}

// ---------------- attention pass 1: si/so per (h,l), qsi/kso column sums ----
// wave handles a row: lane covers cols lane*8..+8 (head = lane>>3).
__global__ __launch_bounds__(256) void attn_pass1(const __bf16* __restrict__ q,
                                                  const __bf16* __restrict__ k,
                                                  const float* __restrict__ qsum,
                                                  const float* __restrict__ ksum,
                                                  float* __restrict__ si_out,
                                                  float* __restrict__ qsi,
                                                  float* __restrict__ kso) {
  __shared__ float lsQ[512], lsK[512];
  const int t = threadIdx.x, lane = t & 63, wv = t >> 6;
  const int c0 = lane * 8;
  lsQ[t] = 0.f; lsQ[t + 256] = 0.f;
  lsK[t] = 0.f; lsK[t + 256] = 0.f;
  __syncthreads();
  float qs[8], ks[8];
#pragma unroll
  for (int j = 0; j < 8; j++) {
    qs[j] = qsum[c0 + j] + EPSF;
    ks[j] = ksum[c0 + j] + EPSF;
  }
  const int h = lane >> 3;
  float qacc[8] = {}, kacc[8] = {};
#pragma unroll 1
  for (int i = 0; i < 8; i++) {
    const int l = blockIdx.x * 32 + wv * 8 + i;
    const b16x8 q8 = *reinterpret_cast<const b16x8*>(q + (size_t)l * 512 + c0);
    const b16x8 k8 = *reinterpret_cast<const b16x8*>(k + (size_t)l * 512 + c0);
    float qf[8], kf[8];
    float p1 = 0.f, p2 = 0.f;
#pragma unroll
    for (int j = 0; j < 8; j++) {
      qf[j] = (float)q8[j]; kf[j] = (float)k8[j];
      p1 += (qf[j] + EPSF) * ks[j];
      p2 += (kf[j] + EPSF) * qs[j];
    }
    p1 += __shfl_xor(p1, 1); p2 += __shfl_xor(p2, 1);
    p1 += __shfl_xor(p1, 2); p2 += __shfl_xor(p2, 2);
    p1 += __shfl_xor(p1, 4); p2 += __shfl_xor(p2, 4);
    const float siv = 1.f / p1, sov = 1.f / p2;
    if ((lane & 7) == 0) si_out[h * L_SEQ + l] = siv;
#pragma unroll
    for (int j = 0; j < 8; j++) { qacc[j] += qf[j] * siv; kacc[j] += kf[j] * sov; }
  }
#pragma unroll
  for (int j = 0; j < 8; j++) {
    atomicAdd(&lsQ[c0 + j], qacc[j]);
    atomicAdd(&lsK[c0 + j], kacc[j]);
  }
  __syncthreads();
  atomicAdd(&qsi[t], lsQ[t]);
  atomicAdd(&qsi[t + 256], lsQ[t + 256]);
  atomicAdd(&kso[t], lsK[t]);
  atomicAdd(&kso[t + 256], lsK[t + 256]);
}

// ---------------- kv: compE inline; kv_raw[h,d,m] = sum_l k*ce*v; sumexp[h] --
__global__ __launch_bounds__(256) void kv_kernel(const __bf16* __restrict__ k,
                                                 const float* __restrict__ v,
                                                 const float* __restrict__ qsi,
                                                 float* __restrict__ kvout,
                                                 float* __restrict__ sumexp) {
  const int h = blockIdx.y, t = threadIdx.x;
  __shared__ float lsK[64 * 64];
  __shared__ float lsV[64 * 64];
  __shared__ float lsRed[256];
  const int r = t >> 2, cq = (t & 3) * 16;
  float qv[16];
#pragma unroll
  for (int j = 0; j < 16; j++) qv[j] = qsi[h * 64 + cq + j] + EPSF;
  const int d = t & 63, mg = t >> 6;
  f32x4 acc4[4] = {};
  float seloc = 0.f;
#pragma unroll 1
  for (int sc = 0; sc < 4; sc++) {
    const int l = blockIdx.x * 256 + sc * 64 + r;
    __syncthreads();
    const b16x8 k8a = *reinterpret_cast<const b16x8*>(k + (size_t)l * 512 + h * 64 + cq);
    const b16x8 k8b = *reinterpret_cast<const b16x8*>(k + (size_t)l * 512 + h * 64 + cq + 8);
    f32x4 v4[4];
#pragma unroll
    for (int jj = 0; jj < 4; jj++)
      v4[jj] = *reinterpret_cast<const f32x4*>(v + (size_t)l * 512 + h * 64 + cq + jj * 4);
    float kf[16];
#pragma unroll
    for (int j = 0; j < 8; j++) { kf[j] = (float)k8a[j]; kf[8 + j] = (float)k8b[j]; }
    float p = 0.f;
#pragma unroll
    for (int j = 0; j < 16; j++) p += (kf[j] + EPSF) * qv[j];
    p += __shfl_xor(p, 1);
    p += __shfl_xor(p, 2);
    p = fminf(fmaxf(p, -1.f), 1.f);
    const float ce = __expf(p);
    if ((t & 3) == 0) seloc += ce;
#pragma unroll
    for (int j = 0; j < 16; j++) lsK[r * 64 + cq + j] = kf[j];
#pragma unroll
    for (int jj = 0; jj < 4; jj++) {
      f32x4 tv = v4[jj] * ce;
      *reinterpret_cast<f32x4*>(&lsV[r * 64 + cq + jj * 4]) = tv;
    }
    __syncthreads();
    for (int rr = 0; rr < 64; rr++) {
      const float kd = lsK[rr * 64 + d];
      const f32x4* lv = reinterpret_cast<const f32x4*>(&lsV[rr * 64 + mg * 16]);
#pragma unroll
      for (int jj = 0; jj < 4; jj++) acc4[jj] += lv[jj] * kd;
    }
  }
  lsRed[t] = ((t & 3) == 0) ? seloc : 0.f;
  __syncthreads();
  for (int s = 128; s > 0; s >>= 1) {
    if (t < s) lsRed[t] += lsRed[t + s];
    __syncthreads();
  }
  if (t == 0) atomicAdd(&sumexp[h], lsRed[0]);
#pragma unroll
  for (int jj = 0; jj < 4; jj++)
#pragma unroll
    for (int e = 0; e < 4; e++)
      atomicAdd(&kvout[h * 4096 + d * 64 + mg * 16 + jj * 4 + e], acc4[jj][e]);
}

// ---------------- o: sal inline; o = (q@kv_raw) * si * sal * (L/sumexp) ------
__global__ __launch_bounds__(256) void o_kernel(const __bf16* __restrict__ q,
                                                const float* __restrict__ kvin,
                                                const float* __restrict__ si,
                                                const float* __restrict__ kso,
                                                const float* __restrict__ sumexp,
                                                __bf16* __restrict__ o) {
  const int h = blockIdx.y;
  const int l0 = blockIdx.x * 32;
  const int t = threadIdx.x;
  __shared__ float lsKV[64 * 64];
  __shared__ float lsQ[32 * 64];
  __shared__ float lsF[32];
  const float Sfac = (float)L_SEQ / sumexp[h];
#pragma unroll
  for (int j = 0; j < 16; j++) lsKV[t + j * 256] = kvin[h * 4096 + t + j * 256];
  const int r = t >> 3, c8 = (t & 7) * 8;
  float ksov[8];
#pragma unroll
  for (int j = 0; j < 8; j++) ksov[j] = kso[h * 64 + c8 + j] + EPSF;
  const b16x8 q8 = *reinterpret_cast<const b16x8*>(q + (size_t)(l0 + r) * 512 + h * 64 + c8);
  float p = 0.f;
#pragma unroll
  for (int j = 0; j < 8; j++) {
    const float qf = (float)q8[j];
    lsQ[r * 64 + c8 + j] = qf;
    p += (qf + EPSF) * ksov[j];
  }
  p += __shfl_xor(p, 1);
  p += __shfl_xor(p, 2);
  p += __shfl_xor(p, 4);
  if ((t & 7) == 0) lsF[r] = sigmoidf_(p) * si[h * L_SEQ + l0 + r] * Sfac;
  __syncthreads();
  const int m = t & 63, rg = t >> 6;
#pragma unroll 1
  for (int i = 0; i < 8; i++) {
    const int rr = rg + i * 4;
    float a = 0.f;
#pragma unroll
    for (int dd = 0; dd < 64; dd++) a += lsQ[rr * 64 + dd] * lsKV[dd * 64 + m];
    o[(size_t)(l0 + rr) * 512 + h * 64 + m] = (__bf16)(a * lsF[rr]);
  }
}

// ---------------------------------------------------------------------------
extern "C" void kernel_launch(void* const* d_in, const int* in_sizes, int n_in,
                              void* d_out, int out_size, void* d_ws, size_t ws_size,
                              hipStream_t stream) {
  const float* x  = (const float*)d_in[0];
  const float* Wq = (const float*)d_in[1];
  const float* bq = (const float*)d_in[2];
  const float* Wk = (const float*)d_in[3];
  const float* bk = (const float*)d_in[4];
  const float* Wv = (const float*)d_in[5];
  const float* bv = (const float*)d_in[6];
  const float* Wo = (const float*)d_in[7];
  const float* bo = (const float*)d_in[8];
  const float* W1 = (const float*)d_in[9];
  const float* b1 = (const float*)d_in[10];
  const float* W2 = (const float*)d_in[11];
  const float* b2 = (const float*)d_in[12];
  const float* g1 = (const float*)d_in[13];
  const float* be1 = (const float*)d_in[14];
  const float* g2 = (const float*)d_in[15];
  const float* be2 = (const float*)d_in[16];
  float* out = (float*)d_out;

  char* ws = (char*)d_ws;
  size_t off = 0;
  auto alloc = [&](size_t bytes) -> char* {
    char* p = ws + off;
    off += (bytes + 255) & ~(size_t)255;
    return p;
  };

  // Region A (134.2 MB), time-multiplexed:
  //   phase 1 (attention): ln1 | qb16 | kb16 | vb | ob
  //   phase 2 (Wo+x2ln2):  sa (2x33.5 MB at offset 0; ob at 83.9 MB still live)
  //   phase 3 (MLP):       act (full region)
  char* regA = alloc(134217728);
  __bf16* ln1  = (__bf16*)regA;                      // 16.78 MB
  __bf16* qb16 = (__bf16*)(regA + 16777216);         // 16.78 MB
  __bf16* kb16 = (__bf16*)(regA + 33554432);         // 16.78 MB
  float*  vb   = (float*)(regA + 50331648);          // 33.55 MB
  __bf16* ob   = (__bf16*)(regA + 83886080);         // 16.78 MB
  float*  sa   = (float*)regA;                       // 67.1 MB (2 splits)
  __bf16* act  = (__bf16*)regA;                      // 134.2 MB

  __bf16* ln2 = (__bf16*)alloc((size_t)32768 * 512 * 2);
  __bf16* Wqkvt = (__bf16*)alloc((size_t)1536 * 512 * 2);
  __bf16* Wot = (__bf16*)alloc((size_t)512 * 512 * 2);
  __bf16* W1t = (__bf16*)alloc((size_t)2048 * 512 * 2);
  __bf16* W2t = (__bf16*)alloc((size_t)512 * 2048 * 2);
  float* biascat = (float*)alloc(1536 * 4);
  float* si = (float*)alloc((size_t)8 * L_SEQ * 4);
  float* stats = (float*)alloc(34880 * 4);  // qsum|ksum|qsi|kso|sumexp(64)|kv
  float* qsum = stats;
  float* ksum = stats + 512;
  float* qsi = stats + 1024;
  float* kso = stats + 1536;
  float* sumexp = stats + 2048;
  float* kvbuf = stats + 2112;

  // weights -> bf16 transposed
  convT<<<dim3(16, 16), 256, 0, stream>>>(Wq, Wqkvt, 512, 512);
  convT<<<dim3(16, 16), 256, 0, stream>>>(Wk, Wqkvt + (size_t)512 * 512, 512, 512);
  convT<<<dim3(16, 16), 256, 0, stream>>>(Wv, Wqkvt + (size_t)1024 * 512, 512, 512);
  convT<<<dim3(16, 16), 256, 0, stream>>>(Wo, Wot, 512, 512);
  convT<<<dim3(64, 16), 256, 0, stream>>>(W1, W1t, 512, 2048);
  convT<<<dim3(16, 64), 256, 0, stream>>>(W2, W2t, 2048, 512);
  biascat_k<<<6, 256, 0, stream>>>(bq, bk, bv, biascat);
  zero_k<<<(34880 + 255) / 256, 256, 0, stream>>>(stats, 34880);

  // LN1 (batch 0 only) -> QKV GEMM (sigmoid q,k -> bf16; colsums fused)
  ln_rows<<<L_SEQ, 128, 0, stream>>>(x, g1, be1, ln1);
  gemm256<0, 0><<<384, 512, 0, stream>>>(ln1, Wqkvt, L_SEQ, 1536, 512,
                                         biascat, vb, qb16, kb16, qsum, ksum);

  // fused attention chain: pass1 (si/so + qsi/kso), kv (+compE+sumexp), o (+sal)
  attn_pass1<<<512, 256, 0, stream>>>(qb16, kb16, qsum, ksum, si, qsi, kso);
  kv_kernel<<<dim3(64, 8), 256, 0, stream>>>(kb16, vb, qsi, kvbuf, sumexp);
  o_kernel<<<dim3(L_SEQ / 32, 8), 256, 0, stream>>>(qb16, kvbuf, si, kso, sumexp, ob);

  // sa = o @ Wo (split-K x2, bias folded into x2ln2)
  gemm256<1, 1><<<dim3(128, 2), 512, 0, stream>>>(ob, Wot, L_SEQ, 512, 512,
                                                  nullptr, sa, nullptr, nullptr,
                                                  nullptr, nullptr);

  // x2 = x + sa0 + sa1 + bo -> d_out; ln2 = LN(x2)
  x2ln2_k<<<2 * L_SEQ, 128, 0, stream>>>(x, sa, sa + (size_t)L_SEQ * 512, bo,
                                         g2, be2, out, ln2);

  // MLP: act = gelu(ln2 @ W1 + b1);  d_out += act @ W2 + b2
  gemm256<2, 0><<<1024, 512, 0, stream>>>(ln2, W1t, 2 * L_SEQ, 2048, 512,
                                          b1, nullptr, act, nullptr, nullptr, nullptr);
  gemm256<3, 0><<<256, 512, 0, stream>>>(act, W2t, 2 * L_SEQ, 512, 2048,
                                         b2, out, nullptr, nullptr, nullptr, nullptr);
}

// Round 5
// 549.150 us; speedup vs baseline: 1.3302x; 1.1624x over previous
//
#include <hip/hip_runtime.h>
#include <hip/hip_bf16.h>
#include <cstdint>
#include <cstddef>

// ---------------------------------------------------------------------------
// FlowformerLayer: LN1 -> flow-attention(batch0) -> +res -> LN2 -> MLP -> +res
// B=2, L=16384, D=512, H=8, DH=64, F=2048
// GEMMs: 256x256 tile, BK=64, 8 waves, 8-phase schedule, counted vmcnt,
//        setprio, XOR-swizzled LDS, XCD swizzle. Wo uses split-K x2.
// Attention chain: 3 passes over bf16 q/k + f32 v; ALL cross-block
// accumulations via private slabs + reduce kernels (no contended atomics —
// round-4 PMC showed 2M atomicAdds = 65 MB write-through + 174 us).
// ---------------------------------------------------------------------------

#define L_SEQ 16384
#define EPSF 1e-6f

typedef __bf16 b16x8 __attribute__((ext_vector_type(8)));
typedef __bf16 b16x4 __attribute__((ext_vector_type(4)));
typedef float  f32x4 __attribute__((ext_vector_type(4)));

#define FENCE() asm volatile("" ::: "memory")
#define BARF()  { FENCE(); __builtin_amdgcn_s_barrier(); FENCE(); }
#define WAITV(n) asm volatile("s_waitcnt vmcnt(" #n ")" ::: "memory")

__device__ __forceinline__ void gload16(const void* g, void* l) {
  __builtin_amdgcn_global_load_lds((const __attribute__((address_space(1))) void*)g,
                                   (__attribute__((address_space(3))) void*)l, 16, 0, 0);
}

__device__ __forceinline__ float sigmoidf_(float x) { return 1.f / (1.f + __expf(-x)); }

// ---------------- weight convert + transpose: dst[n*K+k] = bf16(src[k*N+n])
__global__ __launch_bounds__(256) void convT(const float* __restrict__ src,
                                             __bf16* __restrict__ dst, int K, int N) {
  __shared__ float tile[32][33];
  const int k0 = blockIdx.y * 32, n0 = blockIdx.x * 32;
  const int tx = threadIdx.x & 31, ty = threadIdx.x >> 5;  // 32 x 8
#pragma unroll
  for (int i = 0; i < 32; i += 8) tile[ty + i][tx] = src[(size_t)(k0 + ty + i) * N + n0 + tx];
  __syncthreads();
#pragma unroll
  for (int i = 0; i < 32; i += 8)
    dst[(size_t)(n0 + ty + i) * K + k0 + tx] = (__bf16)tile[tx][ty + i];
}

__global__ __launch_bounds__(256) void biascat_k(const float* __restrict__ bq,
                                                 const float* __restrict__ bk,
                                                 const float* __restrict__ bv,
                                                 float* __restrict__ bc) {
  int i = blockIdx.x * 256 + threadIdx.x;  // 1536 total
  bc[i] = (i < 512) ? bq[i] : (i < 1024) ? bk[i - 512] : bv[i - 1024];
}

__global__ __launch_bounds__(256) void zero_k(float* __restrict__ p, int n) {
  int i = blockIdx.x * 256 + threadIdx.x;
  if (i < n) p[i] = 0.f;
}

// ---------------- LayerNorm over D=512, one row per block (128 thr x float4)
__global__ __launch_bounds__(128) void ln_rows(const float* __restrict__ x,
                                               const float* __restrict__ g,
                                               const float* __restrict__ be,
                                               __bf16* __restrict__ out) {
  const int row = blockIdx.x, t = threadIdx.x;
  const float4 xv = reinterpret_cast<const float4*>(x + (size_t)row * 512)[t];
  float s = xv.x + xv.y + xv.z + xv.w;
  float s2 = xv.x * xv.x + xv.y * xv.y + xv.z * xv.z + xv.w * xv.w;
#pragma unroll
  for (int off = 32; off > 0; off >>= 1) { s += __shfl_down(s, off); s2 += __shfl_down(s2, off); }
  __shared__ float red[4];
  if ((t & 63) == 0) { red[(t >> 6) * 2] = s; red[(t >> 6) * 2 + 1] = s2; }
  __syncthreads();
  const float S = red[0] + red[2], S2 = red[1] + red[3];
  const float mean = S * (1.f / 512.f);
  const float var = S2 * (1.f / 512.f) - mean * mean;
  const float inv = rsqrtf(var + 1e-5f);
  const float4 gv = reinterpret_cast<const float4*>(g)[t];
  const float4 bv = reinterpret_cast<const float4*>(be)[t];
  b16x4 o;
  o[0] = (__bf16)((xv.x - mean) * inv * gv.x + bv.x);
  o[1] = (__bf16)((xv.y - mean) * inv * gv.y + bv.y);
  o[2] = (__bf16)((xv.z - mean) * inv * gv.z + bv.z);
  o[3] = (__bf16)((xv.w - mean) * inv * gv.w + bv.w);
  reinterpret_cast<b16x4*>(out + (size_t)row * 512)[t] = o;
}

// ---------------- x2 = x + sa0 + sa1 + bo (broadcast); d_out=x2; ln2=LN(x2)
__global__ __launch_bounds__(128) void x2ln2_k(const float* __restrict__ x,
                                               const float* __restrict__ sa0,
                                               const float* __restrict__ sa1,
                                               const float* __restrict__ bo,
                                               const float* __restrict__ g,
                                               const float* __restrict__ be,
                                               float* __restrict__ xout,
                                               __bf16* __restrict__ lnout) {
  const int row = blockIdx.x, t = threadIdx.x;
  const int l = row & (L_SEQ - 1);
  float4 xv = reinterpret_cast<const float4*>(x + (size_t)row * 512)[t];
  const float4 s0 = reinterpret_cast<const float4*>(sa0 + (size_t)l * 512)[t];
  const float4 s1 = reinterpret_cast<const float4*>(sa1 + (size_t)l * 512)[t];
  const float4 bb = reinterpret_cast<const float4*>(bo)[t];
  xv.x += s0.x + s1.x + bb.x; xv.y += s0.y + s1.y + bb.y;
  xv.z += s0.z + s1.z + bb.z; xv.w += s0.w + s1.w + bb.w;
  reinterpret_cast<float4*>(xout + (size_t)row * 512)[t] = xv;
  float s = xv.x + xv.y + xv.z + xv.w;
  float s2 = xv.x * xv.x + xv.y * xv.y + xv.z * xv.z + xv.w * xv.w;
#pragma unroll
  for (int off = 32; off > 0; off >>= 1) { s += __shfl_down(s, off); s2 += __shfl_down(s2, off); }
  __shared__ float red[4];
  if ((t & 63) == 0) { red[(t >> 6) * 2] = s; red[(t >> 6) * 2 + 1] = s2; }
  __syncthreads();
  const float S = red[0] + red[2], S2 = red[1] + red[3];
  const float mean = S * (1.f / 512.f);
  const float var = S2 * (1.f / 512.f) - mean * mean;
  const float inv = rsqrtf(var + 1e-5f);
  const float4 gv = reinterpret_cast<const float4*>(g)[t];
  const float4 bv = reinterpret_cast<const float4*>(be)[t];
  b16x4 o;
  o[0] = (__bf16)((xv.x - mean) * inv * gv.x + bv.x);
  o[1] = (__bf16)((xv.y - mean) * inv * gv.y + bv.y);
  o[2] = (__bf16)((xv.z - mean) * inv * gv.z + bv.z);
  o[3] = (__bf16)((xv.w - mean) * inv * gv.w + bv.w);
  reinterpret_cast<b16x4*>(lnout + (size_t)row * 512)[t] = o;
}

// ---------------- GEMM 256x256, 8-phase schedule ----------------
#define DSA(mh, ks)                                                           \
  {                                                                           \
    const int ab = bsel * 16384 + (wr * 128 + (mh) * 64 + fr) * 64;           \
    const int sw = ((((ks) << 2) | kb) ^ l7) << 3;                            \
    av[0] = *reinterpret_cast<const b16x8*>(&lds[ab + sw]);                   \
    av[1] = *reinterpret_cast<const b16x8*>(&lds[ab + 1024 + sw]);            \
    av[2] = *reinterpret_cast<const b16x8*>(&lds[ab + 2048 + sw]);            \
    av[3] = *reinterpret_cast<const b16x8*>(&lds[ab + 3072 + sw]);            \
  }
#define DSB(ks)                                                               \
  {                                                                           \
    const int bb = 32768 + bsel * 16384 + (wc * 64 + fr) * 64;                \
    const int sw = ((((ks) << 2) | kb) ^ l7) << 3;                            \
    bv[0] = *reinterpret_cast<const b16x8*>(&lds[bb + sw]);                   \
    bv[1] = *reinterpret_cast<const b16x8*>(&lds[bb + 1024 + sw]);            \
    bv[2] = *reinterpret_cast<const b16x8*>(&lds[bb + 2048 + sw]);            \
    bv[3] = *reinterpret_cast<const b16x8*>(&lds[bb + 3072 + sw]);            \
  }
#define MM(mh)                                                                \
  __builtin_amdgcn_s_setprio(1);                                              \
  _Pragma("unroll") for (int m = 0; m < 4; m++)                               \
      _Pragma("unroll") for (int n = 0; n < 4; n++) acc[(mh) * 4 + m][n] =    \
      __builtin_amdgcn_mfma_f32_16x16x32_bf16(av[m], bv[n],                   \
                                              acc[(mh) * 4 + m][n], 0, 0, 0); \
  __builtin_amdgcn_s_setprio(0);

// EPI 0: QKV (+biascat, sigmoid q/k -> bf16 h0/h1 + column sums f1/f2; v -> f0)
// EPI 1: SA  (val only -> f0, split-K via blockIdx.y when KSPL)
// EPI 2: GELU(+bias -> bf16 h0, stride N)
// EPI 3: OUT (f0[row,col] += acc + bias)
template <int EPI, int KSPL>
__global__ __launch_bounds__(512) void gemm256(const __bf16* __restrict__ A,
                                               const __bf16* __restrict__ Bt,
                                               const int M, const int N, const int K,
                                               const float* __restrict__ bias,
                                               float* __restrict__ f0,
                                               __bf16* __restrict__ h0,
                                               __bf16* __restrict__ h1,
                                               float* __restrict__ f1,
                                               float* __restrict__ f2) {
  __shared__ alignas(16) __bf16 lds[65536];  // 128 KB

  if constexpr (KSPL) {
    const int z = blockIdx.y;
    A += (size_t)z * (K >> 1);
    Bt += (size_t)z * (K >> 1);
    f0 += (size_t)z * ((size_t)M * N);
  }
  const int nt = KSPL ? (K >> 7) : (K >> 6);

  // XCD-aware block swizzle (all x-grids are %8==0)
  const int nwg = gridDim.x;
  const int orig = blockIdx.x;
  const int cpx = nwg >> 3;
  const int wg = (orig & 7) * cpx + (orig >> 3);
  const int gx = N >> 8;
  const int bm = (wg / gx) << 8;
  const int bn = (wg % gx) << 8;

  const int t = threadIdx.x;
  const int w = t >> 6, lane = t & 63;
  const int wr = w >> 2, wc = w & 3;
  const int lr = lane >> 3;                // staging row-in-group 0..7
  const int sx = (lane & 7) ^ lr;          // pre-swizzled source chunk
  const int fr = lane & 15;                // fragment row select
  const int kb = lane >> 4;                // 0..3 (16B chunk within k-step)
  const int l7 = lane & 7;

  const __bf16* As = A + (size_t)(bm + w * 8 + lr) * K + sx * 8;
  const __bf16* Bs = Bt + (size_t)(bn + w * 8 + lr) * K + sx * 8;

  f32x4 acc[8][4] = {};

  auto STG_A = [&](int s, int j0, int j1) {
    const __bf16* ap = As + (s << 6);
    const int dbase = (s & 1) * 16384 + (w << 9);
    gload16(ap + (size_t)(j0 << 6) * K, &lds[dbase + (j0 << 12)]);
    gload16(ap + (size_t)(j1 << 6) * K, &lds[dbase + (j1 << 12)]);
  };
  auto STG_B = [&](int s, int j0, int j1) {
    const __bf16* bp = Bs + (s << 6);
    const int dbase = 32768 + (s & 1) * 16384 + (w << 9);
    gload16(bp + (size_t)(j0 << 6) * K, &lds[dbase + (j0 << 12)]);
    gload16(bp + (size_t)(j1 << 6) * K, &lds[dbase + (j1 << 12)]);
  };

  // prologue: tile0 fully + tile1.A02; drain tile0, keep tile1.A02 in flight
  STG_A(0, 0, 2);
  STG_B(0, 0, 1);
  STG_B(0, 2, 3);
  STG_A(0, 1, 3);
  STG_A(1, 0, 2);
  WAITV(2);
  BARF();

  for (int s = 0; s < nt; s++) {
    const int bsel = s & 1;
    b16x8 av[4], bv[4];
    // q0
    DSA(0, 0);
    DSB(0);
    if (s + 1 < nt) { STG_B(s + 1, 0, 1); WAITV(4); } else { WAITV(0); }
    BARF();
    MM(0);
    BARF();
    // q1
    DSA(1, 0);
    if (s + 1 < nt) STG_B(s + 1, 2, 3);
    BARF();
    MM(1);
    BARF();
    // q2
    DSA(0, 1);
    DSB(1);
    if (s + 1 < nt) STG_A(s + 1, 1, 3);
    BARF();
    MM(0);
    BARF();
    // q3
    DSA(1, 1);
    if (s + 2 < nt) { STG_A(s + 2, 0, 2); WAITV(4); }
    else if (s + 1 < nt) { WAITV(2); }
    BARF();
    MM(1);
    BARF();
  }

  // epilogue
  const int r0 = kb * 4;
  const int cc = fr;
  if constexpr (EPI == 0) {
    const int which = bn >> 9;  // 0=q, 1=k, 2=v (uniform per block)
    float cs[4] = {0.f, 0.f, 0.f, 0.f};
#pragma unroll
    for (int m = 0; m < 8; m++) {
#pragma unroll
      for (int n = 0; n < 4; n++) {
        const int col = bn + wc * 64 + n * 16 + cc;
        const int c2 = col & 511;
#pragma unroll
        for (int r = 0; r < 4; r++) {
          const int row = bm + wr * 128 + m * 16 + r0 + r;
          float val = acc[m][n][r] + bias[col];
          if (which < 2) {
            val = sigmoidf_(val);
            cs[n] += val;
            ((which == 0) ? h0 : h1)[(size_t)row * 512 + c2] = (__bf16)val;
          } else {
            f0[(size_t)row * 512 + c2] = val;
          }
        }
      }
    }
    if (which < 2) {
      float* sums = (which == 0) ? f1 : f2;
#pragma unroll
      for (int n = 0; n < 4; n++) {
        float s = cs[n];
        s += __shfl_xor(s, 16);
        s += __shfl_xor(s, 32);
        if (kb == 0) atomicAdd(&sums[(bn & 511) + wc * 64 + n * 16 + cc], s);
      }
    }
  } else {
#pragma unroll
    for (int m = 0; m < 8; m++) {
#pragma unroll
      for (int n = 0; n < 4; n++) {
        const int col = bn + wc * 64 + n * 16 + cc;
#pragma unroll
        for (int r = 0; r < 4; r++) {
          const int row = bm + wr * 128 + m * 16 + r0 + r;
          float val = acc[m][n][r];
          if constexpr (EPI == 1) {
            f0[(size_t)row * N + col] = val;
          } else if constexpr (EPI == 2) {
            const float xg = val + bias[col];
            const float gel = 0.5f * xg * (1.f + erff(xg * 0.70710678118f));
            h0[(size_t)row * N + col] = (__bf16)gel;
          } else {
            const size_t idx = (size_t)row * N + col;
            f0[idx] = f0[idx] + val + bias[col];
          }
        }
      }
    }
  }
}

// ---------------- attention pass 1: si/so per (h,l); qsi/kso block partials --
// wave handles a row: lane covers cols lane*8..+8 (head = lane>>3).
__global__ __launch_bounds__(256) void attn_pass1(const __bf16* __restrict__ q,
                                                  const __bf16* __restrict__ k,
                                                  const float* __restrict__ qsum,
                                                  const float* __restrict__ ksum,
                                                  float* __restrict__ si_out,
                                                  float* __restrict__ qkpart) {
  __shared__ float lsQ[512], lsK[512];
  const int t = threadIdx.x, lane = t & 63, wv = t >> 6;
  const int c0 = lane * 8;
  lsQ[t] = 0.f; lsQ[t + 256] = 0.f;
  lsK[t] = 0.f; lsK[t + 256] = 0.f;
  __syncthreads();
  float qs[8], ks[8];
#pragma unroll
  for (int j = 0; j < 8; j++) {
    qs[j] = qsum[c0 + j] + EPSF;
    ks[j] = ksum[c0 + j] + EPSF;
  }
  const int h = lane >> 3;
  float qacc[8] = {}, kacc[8] = {};
#pragma unroll 1
  for (int i = 0; i < 8; i++) {
    const int l = blockIdx.x * 32 + wv * 8 + i;
    const b16x8 q8 = *reinterpret_cast<const b16x8*>(q + (size_t)l * 512 + c0);
    const b16x8 k8 = *reinterpret_cast<const b16x8*>(k + (size_t)l * 512 + c0);
    float qf[8], kf[8];
    float p1 = 0.f, p2 = 0.f;
#pragma unroll
    for (int j = 0; j < 8; j++) {
      qf[j] = (float)q8[j]; kf[j] = (float)k8[j];
      p1 += (qf[j] + EPSF) * ks[j];
      p2 += (kf[j] + EPSF) * qs[j];
    }
    p1 += __shfl_xor(p1, 1); p2 += __shfl_xor(p2, 1);
    p1 += __shfl_xor(p1, 2); p2 += __shfl_xor(p2, 2);
    p1 += __shfl_xor(p1, 4); p2 += __shfl_xor(p2, 4);
    const float siv = 1.f / p1, sov = 1.f / p2;
    if ((lane & 7) == 0) si_out[h * L_SEQ + l] = siv;
#pragma unroll
    for (int j = 0; j < 8; j++) { qacc[j] += qf[j] * siv; kacc[j] += kf[j] * sov; }
  }
#pragma unroll
  for (int j = 0; j < 8; j++) {
    atomicAdd(&lsQ[c0 + j], qacc[j]);   // LDS atomics: 4 waves -> 4-way, cheap
    atomicAdd(&lsK[c0 + j], kacc[j]);
  }
  __syncthreads();
  float* qp = qkpart + (size_t)blockIdx.x * 1024;
  qp[t] = lsQ[t];
  qp[t + 256] = lsQ[t + 256];
  qp[t + 512] = lsK[t];
  qp[t + 768] = lsK[t + 256];
}

// reduce 512 block-partials -> qsi[0..511] | kso[0..511] (contiguous output)
__global__ __launch_bounds__(256) void reduce_qk(const float* __restrict__ qkpart,
                                                 float* __restrict__ outv) {
  const int i = blockIdx.x * 256 + threadIdx.x;  // 0..1023
  float s = 0.f;
#pragma unroll 4
  for (int b = 0; b < 512; b++) s += qkpart[(size_t)b * 1024 + i];
  outv[i] = s;
}

// ---------------- kv partials: compE inline; no atomics -----------------------
// kvpart[(h*64+bx)*4096 + d*64 + m] = sum_{l in block} k[l,hd]*ce[l]*v[l,hm]
__global__ __launch_bounds__(256) void kv_part(const __bf16* __restrict__ k,
                                               const float* __restrict__ v,
                                               const float* __restrict__ qsi,
                                               float* __restrict__ kvpart,
                                               float* __restrict__ separt) {
  const int h = blockIdx.y, bx = blockIdx.x, t = threadIdx.x;
  __shared__ float lsK[64 * 68];
  __shared__ float lsV[64 * 68];
  __shared__ float lsRed[256];
  const int r = t >> 2, cq = (t & 3) * 16;
  float qv[16];
#pragma unroll
  for (int j = 0; j < 16; j++) qv[j] = qsi[h * 64 + cq + j] + EPSF;
  const int d = t & 63, mg = t >> 6;
  f32x4 acc4[4] = {};
  float seloc = 0.f;
#pragma unroll 1
  for (int sc = 0; sc < 4; sc++) {
    const int l = bx * 256 + sc * 64 + r;
    __syncthreads();
    const b16x8 k8a = *reinterpret_cast<const b16x8*>(k + (size_t)l * 512 + h * 64 + cq);
    const b16x8 k8b = *reinterpret_cast<const b16x8*>(k + (size_t)l * 512 + h * 64 + cq + 8);
    f32x4 v4[4];
#pragma unroll
    for (int jj = 0; jj < 4; jj++)
      v4[jj] = *reinterpret_cast<const f32x4*>(v + (size_t)l * 512 + h * 64 + cq + jj * 4);
    float kf[16];
#pragma unroll
    for (int j = 0; j < 8; j++) { kf[j] = (float)k8a[j]; kf[8 + j] = (float)k8b[j]; }
    float p = 0.f;
#pragma unroll
    for (int j = 0; j < 16; j++) p += (kf[j] + EPSF) * qv[j];
    p += __shfl_xor(p, 1);
    p += __shfl_xor(p, 2);
    p = fminf(fmaxf(p, -1.f), 1.f);
    const float ce = __expf(p);
    if ((t & 3) == 0) seloc += ce;
#pragma unroll
    for (int j = 0; j < 16; j++) lsK[r * 68 + cq + j] = kf[j];
#pragma unroll
    for (int jj = 0; jj < 4; jj++)
      *reinterpret_cast<f32x4*>(&lsV[r * 68 + cq + jj * 4]) = v4[jj] * ce;
    __syncthreads();
    for (int rr = 0; rr < 64; rr++) {
      const float kd = lsK[rr * 68 + d];
      const f32x4* lv = reinterpret_cast<const f32x4*>(&lsV[rr * 68 + mg * 16]);
#pragma unroll
      for (int jj = 0; jj < 4; jj++) acc4[jj] += lv[jj] * kd;
    }
  }
  float* kp = kvpart + ((size_t)h * 64 + bx) * 4096;
#pragma unroll
  for (int jj = 0; jj < 4; jj++)
    *reinterpret_cast<f32x4*>(&kp[d * 64 + mg * 16 + jj * 4]) = acc4[jj];
  lsRed[t] = ((t & 3) == 0) ? seloc : 0.f;
  __syncthreads();
  for (int s2 = 128; s2 > 0; s2 >>= 1) {
    if (t < s2) lsRed[t] += lsRed[t + s2];
    __syncthreads();
  }
  if (t == 0) separt[h * 64 + bx] = lsRed[0];
}

// sum 64 kv partial slabs; also reduce separt -> sumexp[h]
__global__ __launch_bounds__(256) void kv_reduce(const float* __restrict__ kvpart,
                                                 const float* __restrict__ separt,
                                                 float* __restrict__ kvout,
                                                 float* __restrict__ sumexp) {
  const int h = blockIdx.y, t = threadIdx.x;
  const int i = blockIdx.x * 256 + t;
  float s = 0.f;
#pragma unroll 4
  for (int b = 0; b < 64; b++) s += kvpart[((size_t)h * 64 + b) * 4096 + i];
  kvout[h * 4096 + i] = s;
  if (blockIdx.x == 0 && t < 64) {
    float e = separt[h * 64 + t];
#pragma unroll
    for (int off2 = 32; off2 > 0; off2 >>= 1) e += __shfl_down(e, off2);
    if (t == 0) sumexp[h] = e;
  }
}

// ---------------- o: sal inline; o = (q@kv_raw) * si * sal * (L/sumexp) ------
__global__ __launch_bounds__(256) void o_kernel(const __bf16* __restrict__ q,
                                                const float* __restrict__ kvin,
                                                const float* __restrict__ si,
                                                const float* __restrict__ kso,
                                                const float* __restrict__ sumexp,
                                                __bf16* __restrict__ o) {
  const int h = blockIdx.y;
  const int l0 = blockIdx.x * 32;
  const int t = threadIdx.x;
  __shared__ float lsKV[64 * 64];
  __shared__ float lsQ[32 * 65];
  __shared__ float lsF[32];
  const float Sfac = (float)L_SEQ / sumexp[h];
#pragma unroll
  for (int j = 0; j < 16; j++) lsKV[t + j * 256] = kvin[h * 4096 + t + j * 256];
  const int r = t >> 3, c8 = (t & 7) * 8;
  float ksov[8];
#pragma unroll
  for (int j = 0; j < 8; j++) ksov[j] = kso[h * 64 + c8 + j] + EPSF;
  const b16x8 q8 = *reinterpret_cast<const b16x8*>(q + (size_t)(l0 + r) * 512 + h * 64 + c8);
  float p = 0.f;
#pragma unroll
  for (int j = 0; j < 8; j++) {
    const float qf = (float)q8[j];
    lsQ[r * 65 + c8 + j] = qf;
    p += (qf + EPSF) * ksov[j];
  }
  p += __shfl_xor(p, 1);
  p += __shfl_xor(p, 2);
  p += __shfl_xor(p, 4);
  if ((t & 7) == 0) lsF[r] = sigmoidf_(p) * si[h * L_SEQ + l0 + r] * Sfac;
  __syncthreads();
  const int m = t & 63, rg = t >> 6;
#pragma unroll 1
  for (int i = 0; i < 8; i++) {
    const int rr = rg + i * 4;
    float a = 0.f;
#pragma unroll
    for (int dd = 0; dd < 64; dd++) a += lsQ[rr * 65 + dd] * lsKV[dd * 64 + m];
    o[(size_t)(l0 + rr) * 512 + h * 64 + m] = (__bf16)(a * lsF[rr]);
  }
}

// ---------------------------------------------------------------------------
extern "C" void kernel_launch(void* const* d_in, const int* in_sizes, int n_in,
                              void* d_out, int out_size, void* d_ws, size_t ws_size,
                              hipStream_t stream) {
  const float* x  = (const float*)d_in[0];
  const float* Wq = (const float*)d_in[1];
  const float* bq = (const float*)d_in[2];
  const float* Wk = (const float*)d_in[3];
  const float* bk = (const float*)d_in[4];
  const float* Wv = (const float*)d_in[5];
  const float* bv = (const float*)d_in[6];
  const float* Wo = (const float*)d_in[7];
  const float* bo = (const float*)d_in[8];
  const float* W1 = (const float*)d_in[9];
  const float* b1 = (const float*)d_in[10];
  const float* W2 = (const float*)d_in[11];
  const float* b2 = (const float*)d_in[12];
  const float* g1 = (const float*)d_in[13];
  const float* be1 = (const float*)d_in[14];
  const float* g2 = (const float*)d_in[15];
  const float* be2 = (const float*)d_in[16];
  float* out = (float*)d_out;

  char* ws = (char*)d_ws;
  size_t off = 0;
  auto alloc = [&](size_t bytes) -> char* {
    char* p = ws + off;
    off += (bytes + 255) & ~(size_t)255;
    return p;
  };

  // Region A (134.2 MB), time-multiplexed:
  //   phase 1 (attention): ln1 | qb16 | kb16 | vb | ob
  //   phase 2 (Wo+x2ln2):  sa (2x33.5 MB at offset 0; ob at 83.9 MB still live)
  //   phase 3 (MLP):       act (full region)
  char* regA = alloc(134217728);
  __bf16* ln1  = (__bf16*)regA;                      // 16.78 MB
  __bf16* qb16 = (__bf16*)(regA + 16777216);         // 16.78 MB
  __bf16* kb16 = (__bf16*)(regA + 33554432);         // 16.78 MB
  float*  vb   = (float*)(regA + 50331648);          // 33.55 MB
  __bf16* ob   = (__bf16*)(regA + 83886080);         // 16.78 MB
  float*  sa   = (float*)regA;                       // 67.1 MB (2 splits)
  __bf16* act  = (__bf16*)regA;                      // 134.2 MB

  __bf16* ln2 = (__bf16*)alloc((size_t)32768 * 512 * 2);
  __bf16* Wqkvt = (__bf16*)alloc((size_t)1536 * 512 * 2);
  __bf16* Wot = (__bf16*)alloc((size_t)512 * 512 * 2);
  __bf16* W1t = (__bf16*)alloc((size_t)2048 * 512 * 2);
  __bf16* W2t = (__bf16*)alloc((size_t)512 * 2048 * 2);
  float* biascat = (float*)alloc(1536 * 4);
  float* si = (float*)alloc((size_t)8 * L_SEQ * 4);
  float* stats = (float*)alloc(34880 * 4);  // qsum|ksum|qsi|kso|sumexp|kv
  float* qsum = stats;
  float* ksum = stats + 512;
  float* qsi = stats + 1024;       // qsi[512] | kso[512] contiguous
  float* kso = stats + 1536;
  float* sumexp = stats + 2048;
  float* kvbuf = stats + 2112;
  float* kvpart = (float*)alloc((size_t)8 * 64 * 4096 * 4);  // 8.39 MB
  float* separt = (float*)alloc(512 * 4);
  float* qkpart = (float*)alloc((size_t)512 * 1024 * 4);     // 2.10 MB

  // weights -> bf16 transposed
  convT<<<dim3(16, 16), 256, 0, stream>>>(Wq, Wqkvt, 512, 512);
  convT<<<dim3(16, 16), 256, 0, stream>>>(Wk, Wqkvt + (size_t)512 * 512, 512, 512);
  convT<<<dim3(16, 16), 256, 0, stream>>>(Wv, Wqkvt + (size_t)1024 * 512, 512, 512);
  convT<<<dim3(16, 16), 256, 0, stream>>>(Wo, Wot, 512, 512);
  convT<<<dim3(64, 16), 256, 0, stream>>>(W1, W1t, 512, 2048);
  convT<<<dim3(16, 64), 256, 0, stream>>>(W2, W2t, 2048, 512);
  biascat_k<<<6, 256, 0, stream>>>(bq, bk, bv, biascat);
  zero_k<<<(2112 + 255) / 256, 256, 0, stream>>>(stats, 2112);  // qsum..sumexp

  // LN1 (batch 0 only) -> QKV GEMM (sigmoid q,k -> bf16; colsums fused)
  ln_rows<<<L_SEQ, 128, 0, stream>>>(x, g1, be1, ln1);
  gemm256<0, 0><<<384, 512, 0, stream>>>(ln1, Wqkvt, L_SEQ, 1536, 512,
                                         biascat, vb, qb16, kb16, qsum, ksum);

  // fused attention chain, slab-reduced (no contended atomics)
  attn_pass1<<<512, 256, 0, stream>>>(qb16, kb16, qsum, ksum, si, qkpart);
  reduce_qk<<<4, 256, 0, stream>>>(qkpart, qsi);
  kv_part<<<dim3(64, 8), 256, 0, stream>>>(kb16, vb, qsi, kvpart, separt);
  kv_reduce<<<dim3(16, 8), 256, 0, stream>>>(kvpart, separt, kvbuf, sumexp);
  o_kernel<<<dim3(L_SEQ / 32, 8), 256, 0, stream>>>(qb16, kvbuf, si, kso, sumexp, ob);

  // sa = o @ Wo (split-K x2, bias folded into x2ln2)
  gemm256<1, 1><<<dim3(128, 2), 512, 0, stream>>>(ob, Wot, L_SEQ, 512, 512,
                                                  nullptr, sa, nullptr, nullptr,
                                                  nullptr, nullptr);

  // x2 = x + sa0 + sa1 + bo -> d_out; ln2 = LN(x2)
  x2ln2_k<<<2 * L_SEQ, 128, 0, stream>>>(x, sa, sa + (size_t)L_SEQ * 512, bo,
                                         g2, be2, out, ln2);

  // MLP: act = gelu(ln2 @ W1 + b1);  d_out += act @ W2 + b2
  gemm256<2, 0><<<1024, 512, 0, stream>>>(ln2, W1t, 2 * L_SEQ, 2048, 512,
                                          b1, nullptr, act, nullptr, nullptr, nullptr);
  gemm256<3, 0><<<256, 512, 0, stream>>>(act, W2t, 2 * L_SEQ, 512, 2048,
                                         b2, out, nullptr, nullptr, nullptr, nullptr);
}

// Round 6
// 514.021 us; speedup vs baseline: 1.4211x; 1.0683x over previous
//
#include <hip/hip_runtime.h>
#include <hip/hip_bf16.h>
#include <cstdint>
#include <cstddef>

// ---------------------------------------------------------------------------
// FlowformerLayer: LN1 -> flow-attention(batch0) -> +res -> LN2 -> MLP -> +res
// B=2, L=16384, D=512, H=8, DH=64, F=2048
// GEMM: 128x128 tile, BK=32, 4 waves, double-buffered 32KB LDS, ONE barrier
// per K-tile, vmcnt drain of 4 prefetch loads, 4 blocks/CU
// (__launch_bounds__(256,4); VGPR+AGPR budget <=128 — round-5 lesson: the
// unified register file counts MFMA acc against occupancy).
// Attention chain: 3 passes over bf16 q/k + f32 v, slab-reduced (no atomics).
// ---------------------------------------------------------------------------

#define L_SEQ 16384
#define EPSF 1e-6f

typedef __bf16 b16x8 __attribute__((ext_vector_type(8)));
typedef __bf16 b16x4 __attribute__((ext_vector_type(4)));
typedef float  f32x4 __attribute__((ext_vector_type(4)));

#define FENCE() asm volatile("" ::: "memory")
#define BARF()  { FENCE(); __builtin_amdgcn_s_barrier(); FENCE(); }
#define WAITV(n) asm volatile("s_waitcnt vmcnt(" #n ")" ::: "memory")

__device__ __forceinline__ void gload16(const void* g, void* l) {
  __builtin_amdgcn_global_load_lds((const __attribute__((address_space(1))) void*)g,
                                   (__attribute__((address_space(3))) void*)l, 16, 0, 0);
}

__device__ __forceinline__ float sigmoidf_(float x) { return 1.f / (1.f + __expf(-x)); }

// ---------------- weight convert + transpose: dst[n*K+k] = bf16(src[k*N+n])
__global__ __launch_bounds__(256) void convT(const float* __restrict__ src,
                                             __bf16* __restrict__ dst, int K, int N) {
  __shared__ float tile[32][33];
  const int k0 = blockIdx.y * 32, n0 = blockIdx.x * 32;
  const int tx = threadIdx.x & 31, ty = threadIdx.x >> 5;  // 32 x 8
#pragma unroll
  for (int i = 0; i < 32; i += 8) tile[ty + i][tx] = src[(size_t)(k0 + ty + i) * N + n0 + tx];
  __syncthreads();
#pragma unroll
  for (int i = 0; i < 32; i += 8)
    dst[(size_t)(n0 + ty + i) * K + k0 + tx] = (__bf16)tile[tx][ty + i];
}

__global__ __launch_bounds__(256) void biascat_k(const float* __restrict__ bq,
                                                 const float* __restrict__ bk,
                                                 const float* __restrict__ bv,
                                                 float* __restrict__ bc) {
  int i = blockIdx.x * 256 + threadIdx.x;  // 1536 total
  bc[i] = (i < 512) ? bq[i] : (i < 1024) ? bk[i - 512] : bv[i - 1024];
}

__global__ __launch_bounds__(256) void zero_k(float* __restrict__ p, int n) {
  int i = blockIdx.x * 256 + threadIdx.x;
  if (i < n) p[i] = 0.f;
}

// ---------------- LayerNorm over D=512, one row per block (128 thr x float4)
__global__ __launch_bounds__(128) void ln_rows(const float* __restrict__ x,
                                               const float* __restrict__ g,
                                               const float* __restrict__ be,
                                               __bf16* __restrict__ out) {
  const int row = blockIdx.x, t = threadIdx.x;
  const float4 xv = reinterpret_cast<const float4*>(x + (size_t)row * 512)[t];
  float s = xv.x + xv.y + xv.z + xv.w;
  float s2 = xv.x * xv.x + xv.y * xv.y + xv.z * xv.z + xv.w * xv.w;
#pragma unroll
  for (int off = 32; off > 0; off >>= 1) { s += __shfl_down(s, off); s2 += __shfl_down(s2, off); }
  __shared__ float red[4];
  if ((t & 63) == 0) { red[(t >> 6) * 2] = s; red[(t >> 6) * 2 + 1] = s2; }
  __syncthreads();
  const float S = red[0] + red[2], S2 = red[1] + red[3];
  const float mean = S * (1.f / 512.f);
  const float var = S2 * (1.f / 512.f) - mean * mean;
  const float inv = rsqrtf(var + 1e-5f);
  const float4 gv = reinterpret_cast<const float4*>(g)[t];
  const float4 bv = reinterpret_cast<const float4*>(be)[t];
  b16x4 o;
  o[0] = (__bf16)((xv.x - mean) * inv * gv.x + bv.x);
  o[1] = (__bf16)((xv.y - mean) * inv * gv.y + bv.y);
  o[2] = (__bf16)((xv.z - mean) * inv * gv.z + bv.z);
  o[3] = (__bf16)((xv.w - mean) * inv * gv.w + bv.w);
  reinterpret_cast<b16x4*>(out + (size_t)row * 512)[t] = o;
}

// ---------------- x2 = x + sa0 + sa1 + bo (broadcast); d_out=x2; ln2=LN(x2)
__global__ __launch_bounds__(128) void x2ln2_k(const float* __restrict__ x,
                                               const float* __restrict__ sa0,
                                               const float* __restrict__ sa1,
                                               const float* __restrict__ bo,
                                               const float* __restrict__ g,
                                               const float* __restrict__ be,
                                               float* __restrict__ xout,
                                               __bf16* __restrict__ lnout) {
  const int row = blockIdx.x, t = threadIdx.x;
  const int l = row & (L_SEQ - 1);
  float4 xv = reinterpret_cast<const float4*>(x + (size_t)row * 512)[t];
  const float4 s0 = reinterpret_cast<const float4*>(sa0 + (size_t)l * 512)[t];
  const float4 s1 = reinterpret_cast<const float4*>(sa1 + (size_t)l * 512)[t];
  const float4 bb = reinterpret_cast<const float4*>(bo)[t];
  xv.x += s0.x + s1.x + bb.x; xv.y += s0.y + s1.y + bb.y;
  xv.z += s0.z + s1.z + bb.z; xv.w += s0.w + s1.w + bb.w;
  reinterpret_cast<float4*>(xout + (size_t)row * 512)[t] = xv;
  float s = xv.x + xv.y + xv.z + xv.w;
  float s2 = xv.x * xv.x + xv.y * xv.y + xv.z * xv.z + xv.w * xv.w;
#pragma unroll
  for (int off = 32; off > 0; off >>= 1) { s += __shfl_down(s, off); s2 += __shfl_down(s2, off); }
  __shared__ float red[4];
  if ((t & 63) == 0) { red[(t >> 6) * 2] = s; red[(t >> 6) * 2 + 1] = s2; }
  __syncthreads();
  const float S = red[0] + red[2], S2 = red[1] + red[3];
  const float mean = S * (1.f / 512.f);
  const float var = S2 * (1.f / 512.f) - mean * mean;
  const float inv = rsqrtf(var + 1e-5f);
  const float4 gv = reinterpret_cast<const float4*>(g)[t];
  const float4 bv = reinterpret_cast<const float4*>(be)[t];
  b16x4 o;
  o[0] = (__bf16)((xv.x - mean) * inv * gv.x + bv.x);
  o[1] = (__bf16)((xv.y - mean) * inv * gv.y + bv.y);
  o[2] = (__bf16)((xv.z - mean) * inv * gv.z + bv.z);
  o[3] = (__bf16)((xv.w - mean) * inv * gv.w + bv.w);
  reinterpret_cast<b16x4*>(lnout + (size_t)row * 512)[t] = o;
}

// ---------------- GEMM 128x128, BK=32, dbuf, 1 barrier/K-tile, 4 blocks/CU --
// LDS layout (elements): A[sel] at sel*4096, B[sel] at 8192+sel*4096.
// Row-major [128][32]; 64B rows are bank-balanced for the fragment reads
// (8 lanes per 4-bank span) — no swizzle needed at BK=32.
// EPI 0: QKV (+biascat, sigmoid q/k -> bf16 h0/h1 + column sums f1/f2; v->f0)
// EPI 1: SA  (val only -> f0, split-K via blockIdx.y when KSPL)
// EPI 2: GELU(+bias -> bf16 h0, stride N)
// EPI 3: OUT (f0[row,col] += acc + bias)
template <int EPI, int KSPL>
__global__ __launch_bounds__(256, 4) void gemm128(const __bf16* __restrict__ A,
                                                  const __bf16* __restrict__ Bt,
                                                  const int M, const int N, const int K,
                                                  const float* __restrict__ bias,
                                                  float* __restrict__ f0,
                                                  __bf16* __restrict__ h0,
                                                  __bf16* __restrict__ h1,
                                                  float* __restrict__ f1,
                                                  float* __restrict__ f2) {
  __shared__ alignas(16) __bf16 lds[16384];  // 32 KB

  if constexpr (KSPL) {
    const int z = blockIdx.y;
    A += (size_t)z * (K >> 1);
    Bt += (size_t)z * (K >> 1);
    f0 += (size_t)z * ((size_t)M * N);
  }
  const int nt = KSPL ? (K >> 6) : (K >> 5);

  // XCD-aware block swizzle (all x-grids are %8==0)
  const int nwg = gridDim.x;
  const int orig = blockIdx.x;
  const int cpx = nwg >> 3;
  const int wg = (orig & 7) * cpx + (orig >> 3);
  const int gx = N >> 7;
  const int bm = (wg / gx) << 7;
  const int bn = (wg % gx) << 7;

  const int t = threadIdx.x;
  const int w = t >> 6, lane = t & 63;
  const int wr = w >> 1, wc = w & 1;
  const int fr = lane & 15;                // fragment row select
  const int kb = lane >> 4;                // 0..3 (8-elem k-chunk)

  // staging: thread t covers row t>>2 (0..63), 16B chunk t&3; 2 instrs each
  // for A and B cover rows 0-63 / 64-127; LDS dest is linear (t*8 elements).
  const __bf16* As = A + (size_t)(bm + (t >> 2)) * K + (t & 3) * 8;
  const __bf16* Bs = Bt + (size_t)(bn + (t >> 2)) * K + (t & 3) * 8;

  f32x4 acc[4][4] = {};

  auto STG = [&](int s) {
    const int sel = (s & 1) * 4096;
    const __bf16* ap = As + (s << 5);
    const __bf16* bp = Bs + (s << 5);
    gload16(ap, &lds[sel + t * 8]);
    gload16(ap + (size_t)64 * K, &lds[sel + 2048 + t * 8]);
    gload16(bp, &lds[8192 + sel + t * 8]);
    gload16(bp + (size_t)64 * K, &lds[8192 + sel + 2048 + t * 8]);
  };

  STG(0);
  WAITV(0);
  BARF();

  for (int s = 0; s < nt; s++) {
    if (s + 1 < nt) STG(s + 1);
    const int ab = (s & 1) * 4096 + (wr * 64 + fr) * 32 + kb * 8;
    const int bb2 = 8192 + (s & 1) * 4096 + (wc * 64 + fr) * 32 + kb * 8;
    b16x8 av[4], bv[4];
#pragma unroll
    for (int m = 0; m < 4; m++)
      av[m] = *reinterpret_cast<const b16x8*>(&lds[ab + m * 512]);
#pragma unroll
    for (int n = 0; n < 4; n++)
      bv[n] = *reinterpret_cast<const b16x8*>(&lds[bb2 + n * 512]);
#pragma unroll
    for (int m = 0; m < 4; m++)
#pragma unroll
      for (int n = 0; n < 4; n++)
        acc[m][n] = __builtin_amdgcn_mfma_f32_16x16x32_bf16(av[m], bv[n], acc[m][n], 0, 0, 0);
    WAITV(0);   // drain the 4 prefetch loads (issued a full K-tile of work ago)
    BARF();     // buf s+1 now valid for ALL waves; buf s free for overwrite
  }

  // epilogue
  const int r0 = kb * 4;
  const int cc = fr;
  if constexpr (EPI == 0) {
    const int which = bn >> 9;  // 0=q, 1=k, 2=v (uniform per block)
    float cs[4] = {0.f, 0.f, 0.f, 0.f};
#pragma unroll
    for (int m = 0; m < 4; m++) {
#pragma unroll
      for (int n = 0; n < 4; n++) {
        const int col = bn + wc * 64 + n * 16 + cc;
        const int c2 = col & 511;
#pragma unroll
        for (int r = 0; r < 4; r++) {
          const int row = bm + wr * 64 + m * 16 + r0 + r;
          float val = acc[m][n][r] + bias[col];
          if (which < 2) {
            val = sigmoidf_(val);
            cs[n] += val;
            ((which == 0) ? h0 : h1)[(size_t)row * 512 + c2] = (__bf16)val;
          } else {
            f0[(size_t)row * 512 + c2] = val;
          }
        }
      }
    }
    if (which < 2) {
      float* sums = (which == 0) ? f1 : f2;
#pragma unroll
      for (int n = 0; n < 4; n++) {
        float s = cs[n];
        s += __shfl_xor(s, 16);
        s += __shfl_xor(s, 32);
        if (kb == 0) atomicAdd(&sums[(bn & 511) + wc * 64 + n * 16 + cc], s);
      }
    }
  } else {
#pragma unroll
    for (int m = 0; m < 4; m++) {
#pragma unroll
      for (int n = 0; n < 4; n++) {
        const int col = bn + wc * 64 + n * 16 + cc;
#pragma unroll
        for (int r = 0; r < 4; r++) {
          const int row = bm + wr * 64 + m * 16 + r0 + r;
          float val = acc[m][n][r];
          if constexpr (EPI == 1) {
            f0[(size_t)row * N + col] = val;
          } else if constexpr (EPI == 2) {
            const float xg = val + bias[col];
            const float gel = 0.5f * xg * (1.f + erff(xg * 0.70710678118f));
            h0[(size_t)row * N + col] = (__bf16)gel;
          } else {
            const size_t idx = (size_t)row * N + col;
            f0[idx] = f0[idx] + val + bias[col];
          }
        }
      }
    }
  }
}

// ---------------- attention pass 1: si/so per (h,l); qsi/kso block partials --
__global__ __launch_bounds__(256) void attn_pass1(const __bf16* __restrict__ q,
                                                  const __bf16* __restrict__ k,
                                                  const float* __restrict__ qsum,
                                                  const float* __restrict__ ksum,
                                                  float* __restrict__ si_out,
                                                  float* __restrict__ qkpart) {
  __shared__ float lsQ[512], lsK[512];
  const int t = threadIdx.x, lane = t & 63, wv = t >> 6;
  const int c0 = lane * 8;
  lsQ[t] = 0.f; lsQ[t + 256] = 0.f;
  lsK[t] = 0.f; lsK[t + 256] = 0.f;
  __syncthreads();
  float qs[8], ks[8];
#pragma unroll
  for (int j = 0; j < 8; j++) {
    qs[j] = qsum[c0 + j] + EPSF;
    ks[j] = ksum[c0 + j] + EPSF;
  }
  const int h = lane >> 3;
  float qacc[8] = {}, kacc[8] = {};
#pragma unroll 1
  for (int i = 0; i < 8; i++) {
    const int l = blockIdx.x * 32 + wv * 8 + i;
    const b16x8 q8 = *reinterpret_cast<const b16x8*>(q + (size_t)l * 512 + c0);
    const b16x8 k8 = *reinterpret_cast<const b16x8*>(k + (size_t)l * 512 + c0);
    float qf[8], kf[8];
    float p1 = 0.f, p2 = 0.f;
#pragma unroll
    for (int j = 0; j < 8; j++) {
      qf[j] = (float)q8[j]; kf[j] = (float)k8[j];
      p1 += (qf[j] + EPSF) * ks[j];
      p2 += (kf[j] + EPSF) * qs[j];
    }
    p1 += __shfl_xor(p1, 1); p2 += __shfl_xor(p2, 1);
    p1 += __shfl_xor(p1, 2); p2 += __shfl_xor(p2, 2);
    p1 += __shfl_xor(p1, 4); p2 += __shfl_xor(p2, 4);
    const float siv = 1.f / p1, sov = 1.f / p2;
    if ((lane & 7) == 0) si_out[h * L_SEQ + l] = siv;
#pragma unroll
    for (int j = 0; j < 8; j++) { qacc[j] += qf[j] * siv; kacc[j] += kf[j] * sov; }
  }
#pragma unroll
  for (int j = 0; j < 8; j++) {
    atomicAdd(&lsQ[c0 + j], qacc[j]);   // LDS atomics: 4 waves, cheap
    atomicAdd(&lsK[c0 + j], kacc[j]);
  }
  __syncthreads();
  float* qp = qkpart + (size_t)blockIdx.x * 1024;
  qp[t] = lsQ[t];
  qp[t + 256] = lsQ[t + 256];
  qp[t + 512] = lsK[t];
  qp[t + 768] = lsK[t + 256];
}

// reduce 512 block-partials -> qsi[0..511] | kso[0..511] (contiguous output)
__global__ __launch_bounds__(256) void reduce_qk(const float* __restrict__ qkpart,
                                                 float* __restrict__ outv) {
  const int i = blockIdx.x * 256 + threadIdx.x;  // 0..1023
  float s = 0.f;
#pragma unroll 4
  for (int b = 0; b < 512; b++) s += qkpart[(size_t)b * 1024 + i];
  outv[i] = s;
}

// ---------------- kv partials: compE inline; no atomics -----------------------
__global__ __launch_bounds__(256) void kv_part(const __bf16* __restrict__ k,
                                               const float* __restrict__ v,
                                               const float* __restrict__ qsi,
                                               float* __restrict__ kvpart,
                                               float* __restrict__ separt) {
  const int h = blockIdx.y, bx = blockIdx.x, t = threadIdx.x;
  __shared__ float lsK[64 * 68];
  __shared__ float lsV[64 * 68];
  __shared__ float lsRed[256];
  const int r = t >> 2, cq = (t & 3) * 16;
  float qv[16];
#pragma unroll
  for (int j = 0; j < 16; j++) qv[j] = qsi[h * 64 + cq + j] + EPSF;
  const int d = t & 63, mg = t >> 6;
  f32x4 acc4[4] = {};
  float seloc = 0.f;
#pragma unroll 1
  for (int sc = 0; sc < 4; sc++) {
    const int l = bx * 256 + sc * 64 + r;
    __syncthreads();
    const b16x8 k8a = *reinterpret_cast<const b16x8*>(k + (size_t)l * 512 + h * 64 + cq);
    const b16x8 k8b = *reinterpret_cast<const b16x8*>(k + (size_t)l * 512 + h * 64 + cq + 8);
    f32x4 v4[4];
#pragma unroll
    for (int jj = 0; jj < 4; jj++)
      v4[jj] = *reinterpret_cast<const f32x4*>(v + (size_t)l * 512 + h * 64 + cq + jj * 4);
    float kf[16];
#pragma unroll
    for (int j = 0; j < 8; j++) { kf[j] = (float)k8a[j]; kf[8 + j] = (float)k8b[j]; }
    float p = 0.f;
#pragma unroll
    for (int j = 0; j < 16; j++) p += (kf[j] + EPSF) * qv[j];
    p += __shfl_xor(p, 1);
    p += __shfl_xor(p, 2);
    p = fminf(fmaxf(p, -1.f), 1.f);
    const float ce = __expf(p);
    if ((t & 3) == 0) seloc += ce;
#pragma unroll
    for (int j = 0; j < 16; j++) lsK[r * 68 + cq + j] = kf[j];
#pragma unroll
    for (int jj = 0; jj < 4; jj++)
      *reinterpret_cast<f32x4*>(&lsV[r * 68 + cq + jj * 4]) = v4[jj] * ce;
    __syncthreads();
    for (int rr = 0; rr < 64; rr++) {
      const float kd = lsK[rr * 68 + d];
      const f32x4* lv = reinterpret_cast<const f32x4*>(&lsV[rr * 68 + mg * 16]);
#pragma unroll
      for (int jj = 0; jj < 4; jj++) acc4[jj] += lv[jj] * kd;
    }
  }
  float* kp = kvpart + ((size_t)h * 64 + bx) * 4096;
#pragma unroll
  for (int jj = 0; jj < 4; jj++)
    *reinterpret_cast<f32x4*>(&kp[d * 64 + mg * 16 + jj * 4]) = acc4[jj];
  lsRed[t] = ((t & 3) == 0) ? seloc : 0.f;
  __syncthreads();
  for (int s2 = 128; s2 > 0; s2 >>= 1) {
    if (t < s2) lsRed[t] += lsRed[t + s2];
    __syncthreads();
  }
  if (t == 0) separt[h * 64 + bx] = lsRed[0];
}

// sum 64 kv partial slabs; also reduce separt -> sumexp[h]
__global__ __launch_bounds__(256) void kv_reduce(const float* __restrict__ kvpart,
                                                 const float* __restrict__ separt,
                                                 float* __restrict__ kvout,
                                                 float* __restrict__ sumexp) {
  const int h = blockIdx.y, t = threadIdx.x;
  const int i = blockIdx.x * 256 + t;
  float s = 0.f;
#pragma unroll 4
  for (int b = 0; b < 64; b++) s += kvpart[((size_t)h * 64 + b) * 4096 + i];
  kvout[h * 4096 + i] = s;
  if (blockIdx.x == 0 && t < 64) {
    float e = separt[h * 64 + t];
#pragma unroll
    for (int off2 = 32; off2 > 0; off2 >>= 1) e += __shfl_down(e, off2);
    if (t == 0) sumexp[h] = e;
  }
}

// ---------------- o: sal inline; o = (q@kv_raw) * si * sal * (L/sumexp) ------
__global__ __launch_bounds__(256) void o_kernel(const __bf16* __restrict__ q,
                                                const float* __restrict__ kvin,
                                                const float* __restrict__ si,
                                                const float* __restrict__ kso,
                                                const float* __restrict__ sumexp,
                                                __bf16* __restrict__ o) {
  const int h = blockIdx.y;
  const int l0 = blockIdx.x * 32;
  const int t = threadIdx.x;
  __shared__ float lsKV[64 * 64];
  __shared__ float lsQ[32 * 65];
  __shared__ float lsF[32];
  const float Sfac = (float)L_SEQ / sumexp[h];
#pragma unroll
  for (int j = 0; j < 16; j++) lsKV[t + j * 256] = kvin[h * 4096 + t + j * 256];
  const int r = t >> 3, c8 = (t & 7) * 8;
  float ksov[8];
#pragma unroll
  for (int j = 0; j < 8; j++) ksov[j] = kso[h * 64 + c8 + j] + EPSF;
  const b16x8 q8 = *reinterpret_cast<const b16x8*>(q + (size_t)(l0 + r) * 512 + h * 64 + c8);
  float p = 0.f;
#pragma unroll
  for (int j = 0; j < 8; j++) {
    const float qf = (float)q8[j];
    lsQ[r * 65 + c8 + j] = qf;
    p += (qf + EPSF) * ksov[j];
  }
  p += __shfl_xor(p, 1);
  p += __shfl_xor(p, 2);
  p += __shfl_xor(p, 4);
  if ((t & 7) == 0) lsF[r] = sigmoidf_(p) * si[h * L_SEQ + l0 + r] * Sfac;
  __syncthreads();
  const int m = t & 63, rg = t >> 6;
#pragma unroll 1
  for (int i = 0; i < 8; i++) {
    const int rr = rg + i * 4;
    float a = 0.f;
#pragma unroll
    for (int dd = 0; dd < 64; dd++) a += lsQ[rr * 65 + dd] * lsKV[dd * 64 + m];
    o[(size_t)(l0 + rr) * 512 + h * 64 + m] = (__bf16)(a * lsF[rr]);
  }
}

// ---------------------------------------------------------------------------
extern "C" void kernel_launch(void* const* d_in, const int* in_sizes, int n_in,
                              void* d_out, int out_size, void* d_ws, size_t ws_size,
                              hipStream_t stream) {
  const float* x  = (const float*)d_in[0];
  const float* Wq = (const float*)d_in[1];
  const float* bq = (const float*)d_in[2];
  const float* Wk = (const float*)d_in[3];
  const float* bk = (const float*)d_in[4];
  const float* Wv = (const float*)d_in[5];
  const float* bv = (const float*)d_in[6];
  const float* Wo = (const float*)d_in[7];
  const float* bo = (const float*)d_in[8];
  const float* W1 = (const float*)d_in[9];
  const float* b1 = (const float*)d_in[10];
  const float* W2 = (const float*)d_in[11];
  const float* b2 = (const float*)d_in[12];
  const float* g1 = (const float*)d_in[13];
  const float* be1 = (const float*)d_in[14];
  const float* g2 = (const float*)d_in[15];
  const float* be2 = (const float*)d_in[16];
  float* out = (float*)d_out;

  char* ws = (char*)d_ws;
  size_t off = 0;
  auto alloc = [&](size_t bytes) -> char* {
    char* p = ws + off;
    off += (bytes + 255) & ~(size_t)255;
    return p;
  };

  // Region A (134.2 MB), time-multiplexed:
  //   phase 1 (attention): ln1 | qb16 | kb16 | vb | ob
  //   phase 2 (Wo+x2ln2):  sa (2x33.5 MB at offset 0; ob at 83.9 MB still live)
  //   phase 3 (MLP):       act (full region)
  char* regA = alloc(134217728);
  __bf16* ln1  = (__bf16*)regA;                      // 16.78 MB
  __bf16* qb16 = (__bf16*)(regA + 16777216);         // 16.78 MB
  __bf16* kb16 = (__bf16*)(regA + 33554432);         // 16.78 MB
  float*  vb   = (float*)(regA + 50331648);          // 33.55 MB
  __bf16* ob   = (__bf16*)(regA + 83886080);         // 16.78 MB
  float*  sa   = (float*)regA;                       // 67.1 MB (2 splits)
  __bf16* act  = (__bf16*)regA;                      // 134.2 MB

  __bf16* ln2 = (__bf16*)alloc((size_t)32768 * 512 * 2);
  __bf16* Wqkvt = (__bf16*)alloc((size_t)1536 * 512 * 2);
  __bf16* Wot = (__bf16*)alloc((size_t)512 * 512 * 2);
  __bf16* W1t = (__bf16*)alloc((size_t)2048 * 512 * 2);
  __bf16* W2t = (__bf16*)alloc((size_t)512 * 2048 * 2);
  float* biascat = (float*)alloc(1536 * 4);
  float* si = (float*)alloc((size_t)8 * L_SEQ * 4);
  float* stats = (float*)alloc(34880 * 4);  // qsum|ksum|qsi|kso|sumexp|kv
  float* qsum = stats;
  float* ksum = stats + 512;
  float* qsi = stats + 1024;       // qsi[512] | kso[512] contiguous
  float* kso = stats + 1536;
  float* sumexp = stats + 2048;
  float* kvbuf = stats + 2112;
  float* kvpart = (float*)alloc((size_t)8 * 64 * 4096 * 4);  // 8.39 MB
  float* separt = (float*)alloc(512 * 4);
  float* qkpart = (float*)alloc((size_t)512 * 1024 * 4);     // 2.10 MB

  // weights -> bf16 transposed
  convT<<<dim3(16, 16), 256, 0, stream>>>(Wq, Wqkvt, 512, 512);
  convT<<<dim3(16, 16), 256, 0, stream>>>(Wk, Wqkvt + (size_t)512 * 512, 512, 512);
  convT<<<dim3(16, 16), 256, 0, stream>>>(Wv, Wqkvt + (size_t)1024 * 512, 512, 512);
  convT<<<dim3(16, 16), 256, 0, stream>>>(Wo, Wot, 512, 512);
  convT<<<dim3(64, 16), 256, 0, stream>>>(W1, W1t, 512, 2048);
  convT<<<dim3(16, 64), 256, 0, stream>>>(W2, W2t, 2048, 512);
  biascat_k<<<6, 256, 0, stream>>>(bq, bk, bv, biascat);
  zero_k<<<(2112 + 255) / 256, 256, 0, stream>>>(stats, 2112);  // qsum..sumexp

  // LN1 (batch 0 only) -> QKV GEMM (sigmoid q,k -> bf16; colsums fused)
  ln_rows<<<L_SEQ, 128, 0, stream>>>(x, g1, be1, ln1);
  gemm128<0, 0><<<1536, 256, 0, stream>>>(ln1, Wqkvt, L_SEQ, 1536, 512,
                                          biascat, vb, qb16, kb16, qsum, ksum);

  // fused attention chain, slab-reduced (no contended atomics)
  attn_pass1<<<512, 256, 0, stream>>>(qb16, kb16, qsum, ksum, si, qkpart);
  reduce_qk<<<4, 256, 0, stream>>>(qkpart, qsi);
  kv_part<<<dim3(64, 8), 256, 0, stream>>>(kb16, vb, qsi, kvpart, separt);
  kv_reduce<<<dim3(16, 8), 256, 0, stream>>>(kvpart, separt, kvbuf, sumexp);
  o_kernel<<<dim3(L_SEQ / 32, 8), 256, 0, stream>>>(qb16, kvbuf, si, kso, sumexp, ob);

  // sa = o @ Wo (split-K x2, bias folded into x2ln2)
  gemm128<1, 1><<<dim3(512, 2), 256, 0, stream>>>(ob, Wot, L_SEQ, 512, 512,
                                                  nullptr, sa, nullptr, nullptr,
                                                  nullptr, nullptr);

  // x2 = x + sa0 + sa1 + bo -> d_out; ln2 = LN(x2)
  x2ln2_k<<<2 * L_SEQ, 128, 0, stream>>>(x, sa, sa + (size_t)L_SEQ * 512, bo,
                                         g2, be2, out, ln2);

  // MLP: act = gelu(ln2 @ W1 + b1);  d_out += act @ W2 + b2
  gemm128<2, 0><<<4096, 256, 0, stream>>>(ln2, W1t, 2 * L_SEQ, 2048, 512,
                                          b1, nullptr, act, nullptr, nullptr, nullptr);
  gemm128<3, 0><<<1024, 256, 0, stream>>>(act, W2t, 2 * L_SEQ, 512, 2048,
                                          b2, out, nullptr, nullptr, nullptr, nullptr);
}